// Round 2
// baseline (1468.369 us; speedup 1.0000x reference)
//
#include <hip/hip_runtime.h>

#define NN 50000
#define NE 800000

// ---------------- kernel 1: edge aggregation for layer 0 --------------------
// one 32-lane group per edge: lane k accumulates edge_attr[e][k] into
// agg_e[dst][k]; lanes 0,1 accumulate node_stats[src][0..1]; lane 0 counts.
__global__ __launch_bounds__(256) void k_edge_agg0(
    const int* __restrict__ ei, const float* __restrict__ ea,
    const float* __restrict__ ns, float* __restrict__ cnt,
    float* __restrict__ agg_h0, float* __restrict__ agg_e) {
  int idx = blockIdx.x * 256 + threadIdx.x;
  int e = idx >> 5, k = idx & 31;
  if (e >= NE) return;
  int d = ei[NE + e];
  unsafeAtomicAdd(&agg_e[d * 32 + k], ea[e * 32 + k]);
  if (k < 2) {
    int s = ei[e];
    unsafeAtomicAdd(&agg_h0[d * 2 + k], ns[s * 2 + k]);
  }
  if (k == 0) unsafeAtomicAdd(&cnt[d], 1.0f);
}

// ---------------- kernel 2: node linear 1 (in=36, out=64) -------------------
// wave handles one node (n uniform per wave), lane = output channel.
__global__ __launch_bounds__(256) void k_node_lin1(
    const float* __restrict__ ns, const float* __restrict__ cnt,
    const float* __restrict__ agg_h0, const float* __restrict__ agg_e,
    const float* __restrict__ W1, const float* __restrict__ b1,
    float* __restrict__ h1) {
  int idx = blockIdx.x * 256 + threadIdx.x;
  int n = idx >> 6, o = idx & 63;
  if (n >= NN) return;
  float inv = 1.0f / fmaxf(cnt[n], 1.0f);
  const float* w = W1 + o * 36;
  float acc = b1[o];
  acc += ns[n * 2 + 0] * w[0] + ns[n * 2 + 1] * w[1];
  acc += agg_h0[n * 2 + 0] * inv * w[2] + agg_h0[n * 2 + 1] * inv * w[3];
#pragma unroll
  for (int k = 0; k < 32; ++k) acc += agg_e[n * 32 + k] * inv * w[4 + k];
  h1[n * 64 + o] = fmaxf(acc, 0.0f);
}

// ---------------- kernel 3: edge aggregation for layer 1 (64 ch) ------------
// one 64-lane wave per edge: coalesced read of h1[src][0..63], HW atomic add
// to agg_h1[dst][0..63].
__global__ __launch_bounds__(256) void k_edge_agg1(
    const int* __restrict__ ei, const float* __restrict__ h1,
    float* __restrict__ agg_h1) {
  int idx = blockIdx.x * 256 + threadIdx.x;
  int e = idx >> 6, k = idx & 63;
  if (e >= NE) return;
  int s = ei[e], d = ei[NE + e];
  unsafeAtomicAdd(&agg_h1[d * 64 + k], h1[s * 64 + k]);
}

// ---------------- kernel 4: node linear 2 (in=160, out=64) ------------------
__global__ __launch_bounds__(256) void k_node_lin2(
    const float* __restrict__ h1, const float* __restrict__ cnt,
    const float* __restrict__ agg_h1, const float* __restrict__ agg_e,
    const float* __restrict__ W2, const float* __restrict__ b2,
    float* __restrict__ h2) {
  int idx = blockIdx.x * 256 + threadIdx.x;
  int n = idx >> 6, o = idx & 63;
  if (n >= NN) return;
  float inv = 1.0f / fmaxf(cnt[n], 1.0f);
  const float* w = W2 + o * 160;
  float acc = b2[o];
#pragma unroll
  for (int k = 0; k < 64; ++k) acc += h1[n * 64 + k] * w[k];
#pragma unroll
  for (int k = 0; k < 64; ++k) acc += agg_h1[n * 64 + k] * inv * w[64 + k];
#pragma unroll
  for (int k = 0; k < 32; ++k) acc += agg_e[n * 32 + k] * inv * w[128 + k];
  h2[n * 64 + o] = fmaxf(acc, 0.0f);
}

// ---------------- kernel 5: per-node classifier partials --------------------
// P[n] = A·h2[n] + bc1 ; Q[n] = B·h2[n]   (A = Wc1[:,0:64], B = Wc1[:,64:128])
// wave per node, lane = output channel; weight addresses wave-uniform.
__global__ __launch_bounds__(256) void k_node_pq(
    const float* __restrict__ h2, const float* __restrict__ Wc1,
    const float* __restrict__ bc1, float* __restrict__ P,
    float* __restrict__ Q) {
  int idx = blockIdx.x * 256 + threadIdx.x;
  int n = idx >> 6, o = idx & 63;
  if (n >= NN) return;
  const float* h = h2 + n * 64;
  const float* wa = Wc1 + o * 160;
  const float* wb = wa + 64;
  float p = bc1[o], q = 0.0f;
#pragma unroll
  for (int k = 0; k < 64; ++k) {
    float hv = h[k];
    p += hv * wa[k];
    q += hv * wb[k];
  }
  P[n * 64 + o] = p;
  Q[n * 64 + o] = q;
}

// ---------------- kernel 6: edge classifier MLP (restructured) --------------
// z = relu(P[s] + Q[d] + C·e), t = relu(Wc2·z + bc2), out = Wc3·t + bc3.
// C = Wc1[:,128:160]. acc[64] in VGPRs, weights via uniform (scalar) loads.
__global__ __launch_bounds__(256) void k_edge_cls(
    const int* __restrict__ ei, const float* __restrict__ ea,
    const float* __restrict__ P, const float* __restrict__ Q,
    const float* __restrict__ Wc1, const float* __restrict__ Wc2,
    const float* __restrict__ bc2, const float* __restrict__ Wc3,
    const float* __restrict__ bc3, float* __restrict__ out) {
  int e = blockIdx.x * 256 + threadIdx.x;
  if (e >= NE) return;
  int s = ei[e], d = ei[NE + e];

  const float4* Ps = (const float4*)(P + s * 64);
  const float4* Qd = (const float4*)(Q + d * 64);
  float acc[64];
#pragma unroll
  for (int c = 0; c < 16; ++c) {
    float4 a = Ps[c];
    float4 b = Qd[c];
    acc[4 * c + 0] = a.x + b.x;
    acc[4 * c + 1] = a.y + b.y;
    acc[4 * c + 2] = a.z + b.z;
    acc[4 * c + 3] = a.w + b.w;
  }

  const float4* ev = (const float4*)(ea + e * 32);
#pragma unroll
  for (int c = 0; c < 8; ++c) {
    float4 r = ev[c];
#pragma unroll
    for (int o = 0; o < 64; ++o) {
      const float4 w = *(const float4*)(Wc1 + o * 160 + 128 + c * 4);
      acc[o] += r.x * w.x + r.y * w.y + r.z * w.z + r.w * w.w;
    }
  }
#pragma unroll
  for (int o = 0; o < 64; ++o) acc[o] = fmaxf(acc[o], 0.0f);

  float result = bc3[0];
  for (int o = 0; o < 32; ++o) {  // o uniform -> scalar weight loads
    float t = bc2[o];
#pragma unroll
    for (int i = 0; i < 64; ++i) t += acc[i] * Wc2[o * 64 + i];
    result += fmaxf(t, 0.0f) * Wc3[o];
  }
  out[e] = result;
}

extern "C" void kernel_launch(void* const* d_in, const int* in_sizes, int n_in,
                              void* d_out, int out_size, void* d_ws, size_t ws_size,
                              hipStream_t stream) {
  // inputs: 0:x(unused) 1:edge_index 2:edge_attr 3:node_stats 4:W1 5:b1 6:W2
  //         7:b2 8:Wc1 9:bc1 10:Wc2 11:bc2 12:Wc3 13:bc3
  const int*   ei  = (const int*)d_in[1];
  const float* ea  = (const float*)d_in[2];
  const float* ns  = (const float*)d_in[3];
  const float* W1  = (const float*)d_in[4];
  const float* b1  = (const float*)d_in[5];
  const float* W2  = (const float*)d_in[6];
  const float* b2  = (const float*)d_in[7];
  const float* Wc1 = (const float*)d_in[8];
  const float* bc1 = (const float*)d_in[9];
  const float* Wc2 = (const float*)d_in[10];
  const float* bc2 = (const float*)d_in[11];
  const float* Wc3 = (const float*)d_in[12];
  const float* bc3 = (const float*)d_in[13];
  float* out = (float*)d_out;

  // workspace layout (floats):
  //   cnt     [NN]      @ 0
  //   agg_h0  [2*NN]    @ NN
  //   agg_e   [32*NN]   @ 3*NN
  //   agg_h1  [64*NN]   @ 35*NN   -> reused as Q after k_node_lin2
  //   h1      [64*NN]   @ 99*NN   -> reused as P after k_node_lin2
  //   h2      [64*NN]   @ 163*NN      (total 227*NN floats = 45.4 MB)
  float* ws     = (float*)d_ws;
  float* cnt    = ws;
  float* agg_h0 = ws + (size_t)NN;
  float* agg_e  = ws + (size_t)3 * NN;
  float* agg_h1 = ws + (size_t)35 * NN;
  float* h1     = ws + (size_t)99 * NN;
  float* h2     = ws + (size_t)163 * NN;
  float* Q      = agg_h1;  // dead after k_node_lin2
  float* P      = h1;      // dead after k_node_lin2

  // zero the atomic-accumulation region (cnt..agg_h1) every call
  hipMemsetAsync(d_ws, 0, (size_t)99 * NN * sizeof(float), stream);

  k_edge_agg0<<<(NE * 32) / 256, 256, 0, stream>>>(ei, ea, ns, cnt, agg_h0, agg_e);
  k_node_lin1<<<(NN * 64 + 255) / 256, 256, 0, stream>>>(ns, cnt, agg_h0, agg_e, W1, b1, h1);
  k_edge_agg1<<<(NE * 64) / 256, 256, 0, stream>>>(ei, h1, agg_h1);
  k_node_lin2<<<(NN * 64 + 255) / 256, 256, 0, stream>>>(h1, cnt, agg_h1, agg_e, W2, b2, h2);
  k_node_pq<<<(NN * 64 + 255) / 256, 256, 0, stream>>>(h2, Wc1, bc1, P, Q);
  k_edge_cls<<<(NE + 255) / 256, 256, 0, stream>>>(ei, ea, P, Q, Wc1, Wc2, bc2, Wc3, bc3, out);
}

// Round 3
// 1165.743 us; speedup vs baseline: 1.2596x; 1.2596x over previous
//
#include <hip/hip_runtime.h>

#define NN 50000
#define NE 800000
#define NB_SCAN 196  // ceil(NN/256)

// ---- workspace layout (4B elems), total 227*NN = 45.4 MB (same as R1) ----
// deg    [NN]  i32 @ 0            (in-degree, survives through lin2)
// agg_h0 [2NN] f32 @ NN
// agg_e  [32NN]f32 @ 3NN
// agg_h1 [64NN]f32 @ 35NN   (reused as Q after lin2)
// h1     [64NN]f32 @ 99NN   (reused as P after lin2)
// h2     [64NN]f32 @ 163NN  -- CSR scratch aliased here (dead before lin2):
//   offs  i32 @ 163NN (NN+1) ; fill i32 @ 165NN (NN)
//   bsums i32 @ 166NN (256)  ; elist i32 @ 167NN (NE)

// ---------------- CSR build --------------------------------------------------
__global__ __launch_bounds__(256) void k_hist(const int* __restrict__ ei,
                                              int* __restrict__ deg) {
  int e = blockIdx.x * 256 + threadIdx.x;
  if (e >= NE) return;
  atomicAdd(&deg[ei[NE + e]], 1);
}

__global__ __launch_bounds__(256) void k_scan1(const int* __restrict__ deg,
                                               int* __restrict__ offs,
                                               int* __restrict__ bsums) {
  __shared__ int sh[256];
  int tid = threadIdx.x;
  int i = blockIdx.x * 256 + tid;
  int v = (i < NN) ? deg[i] : 0;
  int val = v;
  sh[tid] = val;
  __syncthreads();
  for (int ofs = 1; ofs < 256; ofs <<= 1) {
    int t = (tid >= ofs) ? sh[tid - ofs] : 0;
    __syncthreads();
    val += t;
    sh[tid] = val;
    __syncthreads();
  }
  if (i < NN) offs[i] = val - v;           // exclusive within block
  if (tid == 255) bsums[blockIdx.x] = val; // block total
}

__global__ __launch_bounds__(256) void k_scan2(int* __restrict__ bsums) {
  __shared__ int sh[256];
  int tid = threadIdx.x;
  int v = (tid < NB_SCAN) ? bsums[tid] : 0;
  int val = v;
  sh[tid] = val;
  __syncthreads();
  for (int ofs = 1; ofs < 256; ofs <<= 1) {
    int t = (tid >= ofs) ? sh[tid - ofs] : 0;
    __syncthreads();
    val += t;
    sh[tid] = val;
    __syncthreads();
  }
  if (tid < NB_SCAN) bsums[tid] = val - v; // exclusive block bases
}

__global__ __launch_bounds__(256) void k_scan3(int* __restrict__ offs,
                                               const int* __restrict__ bsums) {
  int i = blockIdx.x * 256 + threadIdx.x;
  if (i < NN) offs[i] += bsums[blockIdx.x];
}

__global__ __launch_bounds__(256) void k_scatter(const int* __restrict__ ei,
                                                 const int* __restrict__ offs,
                                                 int* __restrict__ fill,
                                                 int* __restrict__ elist) {
  int e = blockIdx.x * 256 + threadIdx.x;
  if (e >= NE) return;
  int d = ei[NE + e];
  int pos = offs[d] + atomicAdd(&fill[d], 1);
  elist[pos] = e;
}

// ---------------- gather aggregations (atomic-free) --------------------------
// 32-lane group per node: lane k sums ea[e][k]; lanes 0,1 sum ns[src][k].
__global__ __launch_bounds__(256) void k_gather0(
    const int* __restrict__ ei, const float* __restrict__ ea,
    const float* __restrict__ ns, const int* __restrict__ offs,
    const int* __restrict__ deg, const int* __restrict__ elist,
    float* __restrict__ agg_h0, float* __restrict__ agg_e) {
  int idx = blockIdx.x * 256 + threadIdx.x;
  int n = idx >> 5, k = idx & 31;
  if (n >= NN) return;
  int off = offs[n], dg = deg[n];
  float acc = 0.0f, acc_h = 0.0f;
  for (int i = 0; i < dg; ++i) {
    int e = elist[off + i];
    acc += ea[e * 32 + k];
    if (k < 2) acc_h += ns[ei[e] * 2 + k];
  }
  agg_e[n * 32 + k] = acc;
  if (k < 2) agg_h0[n * 2 + k] = acc_h;
}

// wave per node: lane k sums h1[src][k] over in-edges (coalesced 256B reads).
__global__ __launch_bounds__(256) void k_gather1(
    const int* __restrict__ ei, const float* __restrict__ h1,
    const int* __restrict__ offs, const int* __restrict__ deg,
    const int* __restrict__ elist, float* __restrict__ agg_h1) {
  int idx = blockIdx.x * 256 + threadIdx.x;
  int n = idx >> 6, k = idx & 63;
  if (n >= NN) return;
  int off = offs[n], dg = deg[n];
  float acc = 0.0f;
  for (int i = 0; i < dg; ++i) {
    int e = elist[off + i];
    acc += h1[ei[e] * 64 + k];
  }
  agg_h1[n * 64 + k] = acc;
}

// ---------------- node linears ----------------------------------------------
__global__ __launch_bounds__(256) void k_node_lin1(
    const float* __restrict__ ns, const int* __restrict__ deg,
    const float* __restrict__ agg_h0, const float* __restrict__ agg_e,
    const float* __restrict__ W1, const float* __restrict__ b1,
    float* __restrict__ h1) {
  int idx = blockIdx.x * 256 + threadIdx.x;
  int n = idx >> 6, o = idx & 63;
  if (n >= NN) return;
  float inv = 1.0f / fmaxf((float)deg[n], 1.0f);
  const float* w = W1 + o * 36;
  float acc = b1[o];
  acc += ns[n * 2 + 0] * w[0] + ns[n * 2 + 1] * w[1];
  acc += agg_h0[n * 2 + 0] * inv * w[2] + agg_h0[n * 2 + 1] * inv * w[3];
#pragma unroll
  for (int k = 0; k < 32; ++k) acc += agg_e[n * 32 + k] * inv * w[4 + k];
  h1[n * 64 + o] = fmaxf(acc, 0.0f);
}

__global__ __launch_bounds__(256) void k_node_lin2(
    const float* __restrict__ h1, const int* __restrict__ deg,
    const float* __restrict__ agg_h1, const float* __restrict__ agg_e,
    const float* __restrict__ W2, const float* __restrict__ b2,
    float* __restrict__ h2) {
  int idx = blockIdx.x * 256 + threadIdx.x;
  int n = idx >> 6, o = idx & 63;
  if (n >= NN) return;
  float inv = 1.0f / fmaxf((float)deg[n], 1.0f);
  const float* w = W2 + o * 160;
  float acc = b2[o];
#pragma unroll
  for (int k = 0; k < 64; ++k) acc += h1[n * 64 + k] * w[k];
#pragma unroll
  for (int k = 0; k < 64; ++k) acc += agg_h1[n * 64 + k] * inv * w[64 + k];
#pragma unroll
  for (int k = 0; k < 32; ++k) acc += agg_e[n * 32 + k] * inv * w[128 + k];
  h2[n * 64 + o] = fmaxf(acc, 0.0f);
}

// ---------------- per-node classifier partials ------------------------------
__global__ __launch_bounds__(256) void k_node_pq(
    const float* __restrict__ h2, const float* __restrict__ Wc1,
    const float* __restrict__ bc1, float* __restrict__ P,
    float* __restrict__ Q) {
  int idx = blockIdx.x * 256 + threadIdx.x;
  int n = idx >> 6, o = idx & 63;
  if (n >= NN) return;
  const float* h = h2 + n * 64;
  const float* wa = Wc1 + o * 160;
  const float* wb = wa + 64;
  float p = bc1[o], q = 0.0f;
#pragma unroll
  for (int k = 0; k < 64; ++k) {
    float hv = h[k];
    p += hv * wa[k];
    q += hv * wb[k];
  }
  P[n * 64 + o] = p;
  Q[n * 64 + o] = q;
}

// ---------------- edge classifier: wave per edge ----------------------------
// lane = channel. Coalesced P/Q row loads; edge-uniform scalar ea loads;
// LDS-transposed weights (2-way banks = free); shfl-based Wc2 reduction.
__global__ __launch_bounds__(256) void k_edge_cls(
    const int* __restrict__ ei, const float* __restrict__ ea,
    const float* __restrict__ P, const float* __restrict__ Q,
    const float* __restrict__ Wc1, const float* __restrict__ Wc2,
    const float* __restrict__ bc2, const float* __restrict__ Wc3,
    const float* __restrict__ bc3, float* __restrict__ out) {
  __shared__ float WcCt[32 * 64];  // [c][o] = Wc1[o][128+c]
  __shared__ float Wc2t[64 * 32];  // [i][o] = Wc2[o][i]
  __shared__ float wc3s[32], bc2s[32];
  int tid = threadIdx.x;
  for (int t = tid; t < 2048; t += 256) {
    int c = t >> 6, o = t & 63;
    WcCt[c * 64 + o] = Wc1[o * 160 + 128 + c];
  }
  for (int t = tid; t < 2048; t += 256) {
    int i = t >> 5, o = t & 31;
    Wc2t[i * 32 + o] = Wc2[o * 64 + i];
  }
  if (tid < 32) {
    wc3s[tid] = Wc3[tid];
    bc2s[tid] = bc2[tid];
  }
  __syncthreads();

  int lane = tid & 63;
  int wid = __builtin_amdgcn_readfirstlane(tid >> 6);  // wave-uniform
  int w = blockIdx.x * 4 + wid;
  const int NW = 2048 * 4;
  float bc3v = bc3[0];
  int o = lane & 31, h = lane >> 5;

  for (int e = w; e < NE; e += NW) {  // e is SGPR -> ea loads scalarize
    int s = ei[e], d = ei[NE + e];
    float z = P[s * 64 + lane] + Q[d * 64 + lane];  // coalesced 256B rows
    const float* eap = ea + e * 32;                 // uniform address
#pragma unroll
    for (int c = 0; c < 32; ++c) z += eap[c] * WcCt[c * 64 + lane];
    z = fmaxf(z, 0.0f);

    // t_o = sum_i Wc2[o][i] * z_i ; lane (h,o) sums half h, then fold.
    float t = 0.0f;
#pragma unroll
    for (int i = 0; i < 32; ++i) {
      float zi = __shfl(z, h * 32 + i);
      t += zi * Wc2t[(h * 32 + i) * 32 + o];
    }
    t += __shfl_xor(t, 32);
    t = fmaxf(t + bc2s[o], 0.0f);
    float r = t * wc3s[o];
    if (lane >= 32) r = 0.0f;  // dedupe the two copies of each o
#pragma unroll
    for (int m = 1; m < 64; m <<= 1) r += __shfl_xor(r, m);
    if (lane == 0) out[e] = r + bc3v;
  }
}

extern "C" void kernel_launch(void* const* d_in, const int* in_sizes, int n_in,
                              void* d_out, int out_size, void* d_ws, size_t ws_size,
                              hipStream_t stream) {
  const int*   ei  = (const int*)d_in[1];
  const float* ea  = (const float*)d_in[2];
  const float* ns  = (const float*)d_in[3];
  const float* W1  = (const float*)d_in[4];
  const float* b1  = (const float*)d_in[5];
  const float* W2  = (const float*)d_in[6];
  const float* b2  = (const float*)d_in[7];
  const float* Wc1 = (const float*)d_in[8];
  const float* bc1 = (const float*)d_in[9];
  const float* Wc2 = (const float*)d_in[10];
  const float* bc2 = (const float*)d_in[11];
  const float* Wc3 = (const float*)d_in[12];
  const float* bc3 = (const float*)d_in[13];
  float* out = (float*)d_out;

  float* ws     = (float*)d_ws;
  int*   deg    = (int*)ws;
  float* agg_h0 = ws + (size_t)NN;
  float* agg_e  = ws + (size_t)3 * NN;
  float* agg_h1 = ws + (size_t)35 * NN;
  float* h1     = ws + (size_t)99 * NN;
  float* h2     = ws + (size_t)163 * NN;
  // CSR scratch aliased onto h2's region (dead before lin2 writes h2)
  int*   offs   = (int*)(ws + (size_t)163 * NN);
  int*   fill   = (int*)(ws + (size_t)165 * NN);
  int*   bsums  = (int*)(ws + (size_t)166 * NN);
  int*   elist  = (int*)(ws + (size_t)167 * NN);
  float* Q      = agg_h1;  // dead after lin2
  float* P      = h1;      // dead after lin2

  hipMemsetAsync(deg, 0, NN * sizeof(int), stream);
  hipMemsetAsync(fill, 0, NN * sizeof(int), stream);

  k_hist<<<(NE + 255) / 256, 256, 0, stream>>>(ei, deg);
  k_scan1<<<NB_SCAN, 256, 0, stream>>>(deg, offs, bsums);
  k_scan2<<<1, 256, 0, stream>>>(bsums);
  k_scan3<<<NB_SCAN, 256, 0, stream>>>(offs, bsums);
  k_scatter<<<(NE + 255) / 256, 256, 0, stream>>>(ei, offs, fill, elist);

  k_gather0<<<(NN * 32 + 255) / 256, 256, 0, stream>>>(ei, ea, ns, offs, deg,
                                                       elist, agg_h0, agg_e);
  k_node_lin1<<<(NN * 64 + 255) / 256, 256, 0, stream>>>(ns, deg, agg_h0,
                                                         agg_e, W1, b1, h1);
  k_gather1<<<(NN * 64 + 255) / 256, 256, 0, stream>>>(ei, h1, offs, deg,
                                                       elist, agg_h1);
  k_node_lin2<<<(NN * 64 + 255) / 256, 256, 0, stream>>>(h1, deg, agg_h1,
                                                         agg_e, W2, b2, h2);
  k_node_pq<<<(NN * 64 + 255) / 256, 256, 0, stream>>>(h2, Wc1, bc1, P, Q);
  k_edge_cls<<<2048, 256, 0, stream>>>(ei, ea, P, Q, Wc1, Wc2, bc2, Wc3, bc3,
                                       out);
}

// Round 4
// 776.782 us; speedup vs baseline: 1.8903x; 1.5007x over previous
//
#include <hip/hip_runtime.h>
#include <hip/hip_fp16.h>

#define NN 50000
#define NE 800000
#define NB_SCAN 196  // ceil(NN/256)

// ---- workspace layout (4B units), total 227*NN = 45.4 MB ----
// deg    i32 [NN]    @ 0
// agg_h0 f32 [2NN]   @ NN
// agg_e  f32 [32NN]  @ 3NN
// agg_h1 f32 [64NN]  @ 35NN   (dead after lin2 -> Pb @35NN, Qb @67NN, f16)
// h1     f16 [64NN]  @ 99NN..131NN
// weights(transposed) @131NN: W1t(2304) W2t@+4096(10240) WAt@+16384(4096)
//                     WBt@+20480(4096) bsums@+30000(256)
// offs   i32 [NN]    @ 132NN ; fill i32 [NN] @ 133NN
// elist  i32 [NE]    @ 134NN ; slist i32 [NE] @ 150NN..166NN
// h2     f32 [64NN]  @ 163NN..227NN  (clobbers slist tail AFTER gathers: ok)

// ---------------- weight transpose: Wt[k][o] = W[o][k] ----------------------
__global__ __launch_bounds__(256) void k_wt(
    const float* __restrict__ W1, const float* __restrict__ W2,
    const float* __restrict__ Wc1, float* __restrict__ W1t,
    float* __restrict__ W2t, float* __restrict__ WAt,
    float* __restrict__ WBt) {
  int id = blockIdx.x * 256 + threadIdx.x;
  if (id < 36 * 64) {
    int k = id >> 6, o = id & 63;
    W1t[id] = W1[o * 36 + k];
  }
  if (id < 160 * 64) {
    int k = id >> 6, o = id & 63;
    W2t[id] = W2[o * 160 + k];
  }
  if (id < 64 * 64) {
    int k = id >> 6, o = id & 63;
    WAt[id] = Wc1[o * 160 + k];
    WBt[id] = Wc1[o * 160 + 64 + k];
  }
}

// ---------------- CSR build -------------------------------------------------
__global__ __launch_bounds__(256) void k_hist(const int* __restrict__ ei,
                                              int* __restrict__ deg) {
  int e = blockIdx.x * 256 + threadIdx.x;
  if (e >= NE) return;
  atomicAdd(&deg[ei[NE + e]], 1);
}

__global__ __launch_bounds__(256) void k_scan1(const int* __restrict__ deg,
                                               int* __restrict__ offs,
                                               int* __restrict__ bsums) {
  __shared__ int sh[256];
  int tid = threadIdx.x;
  int i = blockIdx.x * 256 + tid;
  int v = (i < NN) ? deg[i] : 0;
  int val = v;
  sh[tid] = val;
  __syncthreads();
  for (int ofs = 1; ofs < 256; ofs <<= 1) {
    int t = (tid >= ofs) ? sh[tid - ofs] : 0;
    __syncthreads();
    val += t;
    sh[tid] = val;
    __syncthreads();
  }
  if (i < NN) offs[i] = val - v;
  if (tid == 255) bsums[blockIdx.x] = val;
}

__global__ __launch_bounds__(256) void k_scan2(int* __restrict__ bsums) {
  __shared__ int sh[256];
  int tid = threadIdx.x;
  int v = (tid < NB_SCAN) ? bsums[tid] : 0;
  int val = v;
  sh[tid] = val;
  __syncthreads();
  for (int ofs = 1; ofs < 256; ofs <<= 1) {
    int t = (tid >= ofs) ? sh[tid - ofs] : 0;
    __syncthreads();
    val += t;
    sh[tid] = val;
    __syncthreads();
  }
  if (tid < NB_SCAN) bsums[tid] = val - v;
}

__global__ __launch_bounds__(256) void k_scan3(int* __restrict__ offs,
                                               const int* __restrict__ bsums) {
  int i = blockIdx.x * 256 + threadIdx.x;
  if (i < NN) offs[i] += bsums[blockIdx.x];
}

// store edge id AND src id -> gathers need no ei indirection
__global__ __launch_bounds__(256) void k_scatter(const int* __restrict__ ei,
                                                 const int* __restrict__ offs,
                                                 int* __restrict__ fill,
                                                 int* __restrict__ elist,
                                                 int* __restrict__ slist) {
  int e = blockIdx.x * 256 + threadIdx.x;
  if (e >= NE) return;
  int d = ei[NE + e];
  int pos = offs[d] + atomicAdd(&fill[d], 1);
  elist[pos] = e;
  slist[pos] = ei[e];
}

// ---------------- gathers (atomic-free, 2-edge unrolled) --------------------
// wave per node: halves process 2 edges/iter, fold via shfl_xor(32).
__global__ __launch_bounds__(256) void k_gather0(
    const float* __restrict__ ea, const float* __restrict__ ns,
    const int* __restrict__ offs, const int* __restrict__ deg,
    const int* __restrict__ elist, const int* __restrict__ slist,
    float* __restrict__ agg_h0, float* __restrict__ agg_e) {
  int idx = blockIdx.x * 256 + threadIdx.x;
  int n = idx >> 6, lane = idx & 63;
  if (n >= NN) return;
  int off = offs[n], dg = deg[n];
  int k = lane & 31, half = lane >> 5;
  float acc = 0.0f, acch = 0.0f;
  int i = 0;
  for (; i + 2 <= dg; i += 2) {
    int e = elist[off + i + half];
    acc += ea[e * 32 + k];
    if (k < 2) acch += ns[slist[off + i + half] * 2 + k];
  }
  if (i < dg && half == 0) {
    int e = elist[off + i];
    acc += ea[e * 32 + k];
    if (k < 2) acch += ns[slist[off + i] * 2 + k];
  }
  acc += __shfl_xor(acc, 32);
  acch += __shfl_xor(acch, 32);
  if (lane < 32) agg_e[n * 32 + lane] = acc;
  if (lane < 2) agg_h0[n * 2 + lane] = acch;
}

// wave per node: lane k sums f16 h1[src][k]; 2 independent rows in flight.
__global__ __launch_bounds__(256) void k_gather1(
    const __half* __restrict__ h1h, const int* __restrict__ offs,
    const int* __restrict__ deg, const int* __restrict__ slist,
    float* __restrict__ agg_h1) {
  int idx = blockIdx.x * 256 + threadIdx.x;
  int n = idx >> 6, lane = idx & 63;
  if (n >= NN) return;
  int off = offs[n], dg = deg[n];
  float acc = 0.0f;
  int i = 0;
  for (; i + 2 <= dg; i += 2) {
    int s0 = slist[off + i], s1 = slist[off + i + 1];
    float a = __half2float(h1h[s0 * 64 + lane]);
    float b = __half2float(h1h[s1 * 64 + lane]);
    acc += a + b;
  }
  if (i < dg) acc += __half2float(h1h[slist[off + i] * 64 + lane]);
  agg_h1[n * 64 + lane] = acc;
}

// ---------------- node linears (coalesced transposed weights) ---------------
__global__ __launch_bounds__(256) void k_node_lin1(
    const float* __restrict__ ns, const int* __restrict__ deg,
    const float* __restrict__ agg_h0, const float* __restrict__ agg_e,
    const float* __restrict__ W1t, const float* __restrict__ b1,
    __half* __restrict__ h1h) {
  int idx = blockIdx.x * 256 + threadIdx.x;
  int n = idx >> 6, o = idx & 63;
  if (n >= NN) return;
  float inv = 1.0f / fmaxf((float)deg[n], 1.0f);
  float acc = b1[o];
  acc += ns[n * 2 + 0] * W1t[0 * 64 + o] + ns[n * 2 + 1] * W1t[1 * 64 + o];
  acc += agg_h0[n * 2 + 0] * inv * W1t[2 * 64 + o] +
         agg_h0[n * 2 + 1] * inv * W1t[3 * 64 + o];
#pragma unroll
  for (int k = 0; k < 32; ++k)
    acc += agg_e[n * 32 + k] * inv * W1t[(4 + k) * 64 + o];
  h1h[n * 64 + o] = __float2half(fmaxf(acc, 0.0f));
}

__global__ __launch_bounds__(256) void k_node_lin2(
    const __half* __restrict__ h1h, const int* __restrict__ deg,
    const float* __restrict__ agg_h1, const float* __restrict__ agg_e,
    const float* __restrict__ W2t, const float* __restrict__ b2,
    float* __restrict__ h2) {
  int idx = blockIdx.x * 256 + threadIdx.x;
  int n = idx >> 6, o = idx & 63;
  if (n >= NN) return;
  float inv = 1.0f / fmaxf((float)deg[n], 1.0f);
  float acc = b2[o];
  const __half2* hp = (const __half2*)(h1h + n * 64);
#pragma unroll
  for (int k2 = 0; k2 < 32; ++k2) {
    float2 hv = __half22float2(hp[k2]);
    acc += hv.x * W2t[(2 * k2) * 64 + o] + hv.y * W2t[(2 * k2 + 1) * 64 + o];
  }
#pragma unroll
  for (int k = 0; k < 64; ++k)
    acc += agg_h1[n * 64 + k] * inv * W2t[(64 + k) * 64 + o];
#pragma unroll
  for (int k = 0; k < 32; ++k)
    acc += agg_e[n * 32 + k] * inv * W2t[(128 + k) * 64 + o];
  h2[n * 64 + o] = fmaxf(acc, 0.0f);
}

// ---------------- per-node classifier partials (f16 out) --------------------
__global__ __launch_bounds__(256) void k_node_pq(
    const float* __restrict__ h2, const float* __restrict__ WAt,
    const float* __restrict__ WBt, const float* __restrict__ bc1,
    __half* __restrict__ Pb, __half* __restrict__ Qb) {
  int idx = blockIdx.x * 256 + threadIdx.x;
  int n = idx >> 6, o = idx & 63;
  if (n >= NN) return;
  const float* h = h2 + n * 64;
  float p = bc1[o], q = 0.0f;
#pragma unroll
  for (int k = 0; k < 64; ++k) {
    float hv = h[k];
    p += hv * WAt[k * 64 + o];
    q += hv * WBt[k * 64 + o];
  }
  Pb[n * 64 + o] = __float2half(p);
  Qb[n * 64 + o] = __float2half(q);
}

// ---------------- edge classifier: wave per 2 edges -------------------------
__global__ __launch_bounds__(256) void k_edge_cls(
    const int* __restrict__ ei, const float* __restrict__ ea,
    const __half* __restrict__ Pb, const __half* __restrict__ Qb,
    const float* __restrict__ Wc1, const float* __restrict__ Wc2,
    const float* __restrict__ bc2, const float* __restrict__ Wc3,
    const float* __restrict__ bc3, float* __restrict__ out) {
  __shared__ float WcCt[32 * 64];  // [c][o] = Wc1[o][128+c]
  __shared__ float Wc2t[64 * 32];  // [i][o] = Wc2[o][i]
  __shared__ float wc3s[32], bc2s[32];
  int tid = threadIdx.x;
  for (int t = tid; t < 2048; t += 256) {
    int c = t >> 6, o = t & 63;
    WcCt[c * 64 + o] = Wc1[o * 160 + 128 + c];
  }
  for (int t = tid; t < 2048; t += 256) {
    int i = t >> 5, o = t & 31;
    Wc2t[i * 32 + o] = Wc2[o * 64 + i];
  }
  if (tid < 32) {
    wc3s[tid] = Wc3[tid];
    bc2s[tid] = bc2[tid];
  }
  __syncthreads();

  int lane = tid & 63;
  int wid = __builtin_amdgcn_readfirstlane(tid >> 6);
  int w = blockIdx.x * 4 + wid;
  const int NW = 2048 * 4;
  float bc3v = bc3[0];
  int o = lane & 31, h = lane >> 5;

  for (int e0 = 2 * w; e0 < NE; e0 += 2 * NW) {
    int e1 = e0 + 1;
    int s0 = ei[e0], d0 = ei[NE + e0];
    int s1 = ei[e1], d1 = ei[NE + e1];
    // 4 independent 128B row gathers in flight
    float z0 = __half2float(Pb[s0 * 64 + lane]) +
               __half2float(Qb[d0 * 64 + lane]);
    float z1 = __half2float(Pb[s1 * 64 + lane]) +
               __half2float(Qb[d1 * 64 + lane]);
    const float* ea0 = ea + (size_t)e0 * 32;  // e uniform -> scalar loads
    const float* ea1 = ea + (size_t)e1 * 32;
#pragma unroll
    for (int c = 0; c < 32; ++c) {
      float wc = WcCt[c * 64 + lane];
      z0 += ea0[c] * wc;
      z1 += ea1[c] * wc;
    }
    z0 = fmaxf(z0, 0.0f);
    z1 = fmaxf(z1, 0.0f);

    float t0 = 0.0f, t1 = 0.0f;
#pragma unroll
    for (int i = 0; i < 32; ++i) {
      float w2 = Wc2t[(h * 32 + i) * 32 + o];
      t0 += __shfl(z0, h * 32 + i) * w2;
      t1 += __shfl(z1, h * 32 + i) * w2;
    }
    t0 += __shfl_xor(t0, 32);
    t1 += __shfl_xor(t1, 32);
    t0 = fmaxf(t0 + bc2s[o], 0.0f);
    t1 = fmaxf(t1 + bc2s[o], 0.0f);
    float r0 = t0 * wc3s[o];
    float r1 = t1 * wc3s[o];
    if (lane >= 32) { r0 = 0.0f; r1 = 0.0f; }
#pragma unroll
    for (int m = 1; m < 64; m <<= 1) {
      r0 += __shfl_xor(r0, m);
      r1 += __shfl_xor(r1, m);
    }
    if (lane == 0) {
      out[e0] = r0 + bc3v;
      out[e1] = r1 + bc3v;
    }
  }
}

extern "C" void kernel_launch(void* const* d_in, const int* in_sizes, int n_in,
                              void* d_out, int out_size, void* d_ws, size_t ws_size,
                              hipStream_t stream) {
  const int*   ei  = (const int*)d_in[1];
  const float* ea  = (const float*)d_in[2];
  const float* ns  = (const float*)d_in[3];
  const float* W1  = (const float*)d_in[4];
  const float* b1  = (const float*)d_in[5];
  const float* W2  = (const float*)d_in[6];
  const float* b2  = (const float*)d_in[7];
  const float* Wc1 = (const float*)d_in[8];
  const float* bc1 = (const float*)d_in[9];
  const float* Wc2 = (const float*)d_in[10];
  const float* bc2 = (const float*)d_in[11];
  const float* Wc3 = (const float*)d_in[12];
  const float* bc3 = (const float*)d_in[13];
  float* out = (float*)d_out;

  float*  ws     = (float*)d_ws;
  int*    deg    = (int*)ws;
  float*  agg_h0 = ws + (size_t)NN;
  float*  agg_e  = ws + (size_t)3 * NN;
  float*  agg_h1 = ws + (size_t)35 * NN;
  __half* Pb     = (__half*)(ws + (size_t)35 * NN);   // aliases agg_h1 (dead)
  __half* Qb     = (__half*)(ws + (size_t)67 * NN);
  __half* h1h    = (__half*)(ws + (size_t)99 * NN);
  float*  W1t    = ws + (size_t)131 * NN;
  float*  W2t    = W1t + 4096;
  float*  WAt    = W1t + 16384;
  float*  WBt    = W1t + 20480;
  int*    bsums  = (int*)(W1t + 30000);
  int*    offs   = (int*)(ws + (size_t)132 * NN);
  int*    fill   = (int*)(ws + (size_t)133 * NN);
  int*    elist  = (int*)(ws + (size_t)134 * NN);
  int*    slist  = (int*)(ws + (size_t)150 * NN);
  float*  h2     = ws + (size_t)163 * NN;  // clobbers slist tail after gathers

  hipMemsetAsync(deg, 0, NN * sizeof(int), stream);
  hipMemsetAsync(fill, 0, NN * sizeof(int), stream);

  k_wt<<<40, 256, 0, stream>>>(W1, W2, Wc1, W1t, W2t, WAt, WBt);
  k_hist<<<(NE + 255) / 256, 256, 0, stream>>>(ei, deg);
  k_scan1<<<NB_SCAN, 256, 0, stream>>>(deg, offs, bsums);
  k_scan2<<<1, 256, 0, stream>>>(bsums);
  k_scan3<<<NB_SCAN, 256, 0, stream>>>(offs, bsums);
  k_scatter<<<(NE + 255) / 256, 256, 0, stream>>>(ei, offs, fill, elist, slist);

  k_gather0<<<(NN * 64 + 255) / 256, 256, 0, stream>>>(ea, ns, offs, deg,
                                                       elist, slist, agg_h0,
                                                       agg_e);
  k_node_lin1<<<(NN * 64 + 255) / 256, 256, 0, stream>>>(ns, deg, agg_h0,
                                                         agg_e, W1t, b1, h1h);
  k_gather1<<<(NN * 64 + 255) / 256, 256, 0, stream>>>(h1h, offs, deg, slist,
                                                       agg_h1);
  k_node_lin2<<<(NN * 64 + 255) / 256, 256, 0, stream>>>(h1h, deg, agg_h1,
                                                         agg_e, W2t, b2, h2);
  k_node_pq<<<(NN * 64 + 255) / 256, 256, 0, stream>>>(h2, WAt, WBt, bc1, Pb,
                                                       Qb);
  k_edge_cls<<<2048, 256, 0, stream>>>(ei, ea, Pb, Qb, Wc1, Wc2, bc2, Wc3,
                                       bc3, out);
}

// Round 5
// 476.586 us; speedup vs baseline: 3.0810x; 1.6299x over previous
//
#include <hip/hip_runtime.h>
#include <hip/hip_fp16.h>

#define NN 50000
#define NE 800000
#define NB_SCAN 196  // ceil(NN/256)

typedef _Float16 f16x8 __attribute__((ext_vector_type(8)));
typedef float f32x4 __attribute__((ext_vector_type(4)));
union U4 { uint4 u; f16x8 f; __half2 h2[4]; };

// ---- workspace layout (4B units), total 227*NN = 45.4 MB ----
// (identical to R3; see per-buffer pointers in kernel_launch)

// ---------------- weight transpose: Wt[k][o] = W[o][k] ----------------------
__global__ __launch_bounds__(256) void k_wt(
    const float* __restrict__ W1, const float* __restrict__ W2,
    const float* __restrict__ Wc1, float* __restrict__ W1t,
    float* __restrict__ W2t, float* __restrict__ WAt,
    float* __restrict__ WBt) {
  int id = blockIdx.x * 256 + threadIdx.x;
  if (id < 36 * 64) {
    int k = id >> 6, o = id & 63;
    W1t[id] = W1[o * 36 + k];
  }
  if (id < 160 * 64) {
    int k = id >> 6, o = id & 63;
    W2t[id] = W2[o * 160 + k];
  }
  if (id < 64 * 64) {
    int k = id >> 6, o = id & 63;
    WAt[id] = Wc1[o * 160 + k];
    WBt[id] = Wc1[o * 160 + 64 + k];
  }
}

// ---------------- CSR build -------------------------------------------------
__global__ __launch_bounds__(256) void k_hist(const int* __restrict__ ei,
                                              int* __restrict__ deg) {
  int e = blockIdx.x * 256 + threadIdx.x;
  if (e >= NE) return;
  atomicAdd(&deg[ei[NE + e]], 1);
}

__global__ __launch_bounds__(256) void k_scan1(const int* __restrict__ deg,
                                               int* __restrict__ offs,
                                               int* __restrict__ bsums) {
  __shared__ int sh[256];
  int tid = threadIdx.x;
  int i = blockIdx.x * 256 + tid;
  int v = (i < NN) ? deg[i] : 0;
  int val = v;
  sh[tid] = val;
  __syncthreads();
  for (int ofs = 1; ofs < 256; ofs <<= 1) {
    int t = (tid >= ofs) ? sh[tid - ofs] : 0;
    __syncthreads();
    val += t;
    sh[tid] = val;
    __syncthreads();
  }
  if (i < NN) offs[i] = val - v;
  if (tid == 255) bsums[blockIdx.x] = val;
}

__global__ __launch_bounds__(256) void k_scan2(int* __restrict__ bsums) {
  __shared__ int sh[256];
  int tid = threadIdx.x;
  int v = (tid < NB_SCAN) ? bsums[tid] : 0;
  int val = v;
  sh[tid] = val;
  __syncthreads();
  for (int ofs = 1; ofs < 256; ofs <<= 1) {
    int t = (tid >= ofs) ? sh[tid - ofs] : 0;
    __syncthreads();
    val += t;
    sh[tid] = val;
    __syncthreads();
  }
  if (tid < NB_SCAN) bsums[tid] = val - v;
}

__global__ __launch_bounds__(256) void k_scan3(int* __restrict__ offs,
                                               const int* __restrict__ bsums) {
  int i = blockIdx.x * 256 + threadIdx.x;
  if (i < NN) offs[i] += bsums[blockIdx.x];
}

__global__ __launch_bounds__(256) void k_scatter(const int* __restrict__ ei,
                                                 const int* __restrict__ offs,
                                                 int* __restrict__ fill,
                                                 int* __restrict__ elist,
                                                 int* __restrict__ slist) {
  int e = blockIdx.x * 256 + threadIdx.x;
  if (e >= NE) return;
  int d = ei[NE + e];
  int pos = offs[d] + atomicAdd(&fill[d], 1);
  elist[pos] = e;
  slist[pos] = ei[e];
}

// ---------------- gathers (atomic-free) -------------------------------------
__global__ __launch_bounds__(256) void k_gather0(
    const float* __restrict__ ea, const float* __restrict__ ns,
    const int* __restrict__ offs, const int* __restrict__ deg,
    const int* __restrict__ elist, const int* __restrict__ slist,
    float* __restrict__ agg_h0, float* __restrict__ agg_e) {
  int idx = blockIdx.x * 256 + threadIdx.x;
  int n = idx >> 6, lane = idx & 63;
  if (n >= NN) return;
  int off = offs[n], dg = deg[n];
  int k = lane & 31, half = lane >> 5;
  float acc = 0.0f, acch = 0.0f;
  int i = 0;
  for (; i + 2 <= dg; i += 2) {
    int e = elist[off + i + half];
    acc += ea[e * 32 + k];
    if (k < 2) acch += ns[slist[off + i + half] * 2 + k];
  }
  if (i < dg && half == 0) {
    int e = elist[off + i];
    acc += ea[e * 32 + k];
    if (k < 2) acch += ns[slist[off + i] * 2 + k];
  }
  acc += __shfl_xor(acc, 32);
  acch += __shfl_xor(acch, 32);
  if (lane < 32) agg_e[n * 32 + lane] = acc;
  if (lane < 2) agg_h0[n * 2 + lane] = acch;
}

__global__ __launch_bounds__(256) void k_gather1(
    const __half* __restrict__ h1h, const int* __restrict__ offs,
    const int* __restrict__ deg, const int* __restrict__ slist,
    float* __restrict__ agg_h1) {
  int idx = blockIdx.x * 256 + threadIdx.x;
  int n = idx >> 6, lane = idx & 63;
  if (n >= NN) return;
  int off = offs[n], dg = deg[n];
  float acc = 0.0f;
  int i = 0;
  for (; i + 2 <= dg; i += 2) {
    int s0 = slist[off + i], s1 = slist[off + i + 1];
    float a = __half2float(h1h[s0 * 64 + lane]);
    float b = __half2float(h1h[s1 * 64 + lane]);
    acc += a + b;
  }
  if (i < dg) acc += __half2float(h1h[slist[off + i] * 64 + lane]);
  agg_h1[n * 64 + lane] = acc;
}

// ---------------- node linears ----------------------------------------------
__global__ __launch_bounds__(256) void k_node_lin1(
    const float* __restrict__ ns, const int* __restrict__ deg,
    const float* __restrict__ agg_h0, const float* __restrict__ agg_e,
    const float* __restrict__ W1t, const float* __restrict__ b1,
    __half* __restrict__ h1h) {
  int idx = blockIdx.x * 256 + threadIdx.x;
  int n = idx >> 6, o = idx & 63;
  if (n >= NN) return;
  float inv = 1.0f / fmaxf((float)deg[n], 1.0f);
  float acc = b1[o];
  acc += ns[n * 2 + 0] * W1t[0 * 64 + o] + ns[n * 2 + 1] * W1t[1 * 64 + o];
  acc += agg_h0[n * 2 + 0] * inv * W1t[2 * 64 + o] +
         agg_h0[n * 2 + 1] * inv * W1t[3 * 64 + o];
#pragma unroll
  for (int k = 0; k < 32; ++k)
    acc += agg_e[n * 32 + k] * inv * W1t[(4 + k) * 64 + o];
  h1h[n * 64 + o] = __float2half(fmaxf(acc, 0.0f));
}

__global__ __launch_bounds__(256) void k_node_lin2(
    const __half* __restrict__ h1h, const int* __restrict__ deg,
    const float* __restrict__ agg_h1, const float* __restrict__ agg_e,
    const float* __restrict__ W2t, const float* __restrict__ b2,
    float* __restrict__ h2) {
  int idx = blockIdx.x * 256 + threadIdx.x;
  int n = idx >> 6, o = idx & 63;
  if (n >= NN) return;
  float inv = 1.0f / fmaxf((float)deg[n], 1.0f);
  float acc = b2[o];
  const __half2* hp = (const __half2*)(h1h + n * 64);
#pragma unroll
  for (int k2 = 0; k2 < 32; ++k2) {
    float2 hv = __half22float2(hp[k2]);
    acc += hv.x * W2t[(2 * k2) * 64 + o] + hv.y * W2t[(2 * k2 + 1) * 64 + o];
  }
#pragma unroll
  for (int k = 0; k < 64; ++k)
    acc += agg_h1[n * 64 + k] * inv * W2t[(64 + k) * 64 + o];
#pragma unroll
  for (int k = 0; k < 32; ++k)
    acc += agg_e[n * 32 + k] * inv * W2t[(128 + k) * 64 + o];
  h2[n * 64 + o] = fmaxf(acc, 0.0f);
}

// ---------------- per-node classifier partials (f16 out) --------------------
__global__ __launch_bounds__(256) void k_node_pq(
    const float* __restrict__ h2, const float* __restrict__ WAt,
    const float* __restrict__ WBt, const float* __restrict__ bc1,
    __half* __restrict__ Pb, __half* __restrict__ Qb) {
  int idx = blockIdx.x * 256 + threadIdx.x;
  int n = idx >> 6, o = idx & 63;
  if (n >= NN) return;
  const float* h = h2 + n * 64;
  float p = bc1[o], q = 0.0f;
#pragma unroll
  for (int k = 0; k < 64; ++k) {
    float hv = h[k];
    p += hv * WAt[k * 64 + o];
    q += hv * WBt[k * 64 + o];
  }
  Pb[n * 64 + o] = __float2half(p);
  Qb[n * 64 + o] = __float2half(q);
}

// ---------------- edge classifier: MFMA, 64-edge tasks per wave -------------
// Per 16-edge M-tile: Ce[16][64] = f16(ea)[16][32] @ Ct (4 MFMAs, per-wave LDS)
// z-frag = f16(relu(P[s] + Q[d] + Ce))  assembled directly in A-layout
// t[16][32] = z[16][64] @ Wc2^T (4 MFMAs) ; out = relu(t+bc2)·Wc3 + bc3.
// lane roles: col = lane&15 -> edge-in-tile (A rows / C cols), quad = lane>>4.
#define CLS_BLOCKS 1563  // 6252 waves, 2 tasks each (12500 tasks)
__global__ __launch_bounds__(256) void k_edge_cls(
    const int* __restrict__ ei, const float* __restrict__ ea,
    const __half* __restrict__ Pb, const __half* __restrict__ Qb,
    const float* __restrict__ Wc1, const float* __restrict__ Wc2,
    const float* __restrict__ bc2, const float* __restrict__ Wc3,
    const float* __restrict__ bc3, float* __restrict__ out) {
  __shared__ float Zt[4][16 * 68];  // per-wave Ce tile [edge][ch], pitch 68
  int tid = threadIdx.x;
  int lane = tid & 63, wid = tid >> 6;
  int col = lane & 15, quad = lane >> 4;
  float* zl = &Zt[wid][0];

  // B-frags, loaded once. Ce GEMM: B^T[ch][c] = Wc1[ch*160+128+c].
  f16x8 ctF[4];
#pragma unroll
  for (int nt = 0; nt < 4; ++nt) {
    const float* p = Wc1 + (nt * 16 + col) * 160 + 128 + quad * 8;
    U4 u;
    u.h2[0] = __floats2half2_rn(p[0], p[1]);
    u.h2[1] = __floats2half2_rn(p[2], p[3]);
    u.h2[2] = __floats2half2_rn(p[4], p[5]);
    u.h2[3] = __floats2half2_rn(p[6], p[7]);
    ctF[nt] = u.f;
  }
  // t GEMM: B^T[o][i] = Wc2[o*64+i] (already [N][K] row-major).
  f16x8 w2F[2][2];
#pragma unroll
  for (int nt = 0; nt < 2; ++nt)
#pragma unroll
    for (int ks = 0; ks < 2; ++ks) {
      const float* p = Wc2 + (nt * 16 + col) * 64 + ks * 32 + quad * 8;
      U4 u;
      u.h2[0] = __floats2half2_rn(p[0], p[1]);
      u.h2[1] = __floats2half2_rn(p[2], p[3]);
      u.h2[2] = __floats2half2_rn(p[4], p[5]);
      u.h2[3] = __floats2half2_rn(p[6], p[7]);
      w2F[nt][ks] = u.f;
    }
  float wc3v0 = Wc3[col], wc3v1 = Wc3[16 + col];
  float bc2v0 = bc2[col], bc2v1 = bc2[16 + col];
  float bc3v = bc3[0];

  int gw = blockIdx.x * 4 + wid;
  for (int task = gw; task < NE / 64; task += CLS_BLOCKS * 4) {
    int tb = task * 64;
#pragma unroll
    for (int mt = 0; mt < 4; ++mt) {
      int eb = tb + mt * 16;
      int e = eb + col;
      int s = ei[e], d = ei[NE + e];

      // --- Ce GEMM: A-frag from ea (f32 -> f16) ---
      const float* eap = ea + (size_t)e * 32 + quad * 8;
      float4 a0 = *(const float4*)(eap);
      float4 a1 = *(const float4*)(eap + 4);
      U4 ua;
      ua.h2[0] = __floats2half2_rn(a0.x, a0.y);
      ua.h2[1] = __floats2half2_rn(a0.z, a0.w);
      ua.h2[2] = __floats2half2_rn(a1.x, a1.y);
      ua.h2[3] = __floats2half2_rn(a1.z, a1.w);
      f32x4 zero = {0.f, 0.f, 0.f, 0.f};
      f32x4 ce[4];
#pragma unroll
      for (int nt = 0; nt < 4; ++nt)
        ce[nt] = __builtin_amdgcn_mfma_f32_16x16x32_f16(ua.f, ctF[nt], zero,
                                                        0, 0, 0);
      // scatter C-frag to LDS tile: [row=quad*4+j][ch=nt*16+col]
#pragma unroll
      for (int nt = 0; nt < 4; ++nt)
#pragma unroll
        for (int j = 0; j < 4; ++j)
          zl[(quad * 4 + j) * 68 + nt * 16 + col] = ce[nt][j];

      // --- assemble z (A-layout) + t GEMM ---
      const __half* prow = Pb + (size_t)s * 64 + quad * 8;
      const __half* qrow = Qb + (size_t)d * 64 + quad * 8;
      f32x4 tacc0 = zero, tacc1 = zero;
#pragma unroll
      for (int ks = 0; ks < 2; ++ks) {
        U4 up, uq;
        up.u = *(const uint4*)(prow + ks * 32);
        uq.u = *(const uint4*)(qrow + ks * 32);
        const float* zc = zl + col * 68 + ks * 32 + quad * 8;
        float4 c0 = *(const float4*)(zc);
        float4 c1 = *(const float4*)(zc + 4);
        U4 uz;
        {
          float2 pf, qf;
          pf = __half22float2(up.h2[0]); qf = __half22float2(uq.h2[0]);
          uz.h2[0] = __floats2half2_rn(fmaxf(pf.x + qf.x + c0.x, 0.f),
                                       fmaxf(pf.y + qf.y + c0.y, 0.f));
          pf = __half22float2(up.h2[1]); qf = __half22float2(uq.h2[1]);
          uz.h2[1] = __floats2half2_rn(fmaxf(pf.x + qf.x + c0.z, 0.f),
                                       fmaxf(pf.y + qf.y + c0.w, 0.f));
          pf = __half22float2(up.h2[2]); qf = __half22float2(uq.h2[2]);
          uz.h2[2] = __floats2half2_rn(fmaxf(pf.x + qf.x + c1.x, 0.f),
                                       fmaxf(pf.y + qf.y + c1.y, 0.f));
          pf = __half22float2(up.h2[3]); qf = __half22float2(uq.h2[3]);
          uz.h2[3] = __floats2half2_rn(fmaxf(pf.x + qf.x + c1.z, 0.f),
                                       fmaxf(pf.y + qf.y + c1.w, 0.f));
        }
        tacc0 = __builtin_amdgcn_mfma_f32_16x16x32_f16(uz.f, w2F[0][ks],
                                                       tacc0, 0, 0, 0);
        tacc1 = __builtin_amdgcn_mfma_f32_16x16x32_f16(uz.f, w2F[1][ks],
                                                       tacc1, 0, 0, 0);
      }

      // --- epilogue: out = relu(t + bc2) . Wc3 + bc3 ---
      float vj[4];
#pragma unroll
      for (int j = 0; j < 4; ++j) {
        float t0 = fmaxf(tacc0[j] + bc2v0, 0.f);
        float t1 = fmaxf(tacc1[j] + bc2v1, 0.f);
        vj[j] = t0 * wc3v0 + t1 * wc3v1;
      }
#pragma unroll
      for (int m = 1; m < 16; m <<= 1) {
#pragma unroll
        for (int j = 0; j < 4; ++j) vj[j] += __shfl_xor(vj[j], m);
      }
      if (col == 0) {
#pragma unroll
        for (int j = 0; j < 4; ++j) out[eb + quad * 4 + j] = vj[j] + bc3v;
      }
    }
  }
}

extern "C" void kernel_launch(void* const* d_in, const int* in_sizes, int n_in,
                              void* d_out, int out_size, void* d_ws, size_t ws_size,
                              hipStream_t stream) {
  const int*   ei  = (const int*)d_in[1];
  const float* ea  = (const float*)d_in[2];
  const float* ns  = (const float*)d_in[3];
  const float* W1  = (const float*)d_in[4];
  const float* b1  = (const float*)d_in[5];
  const float* W2  = (const float*)d_in[6];
  const float* b2  = (const float*)d_in[7];
  const float* Wc1 = (const float*)d_in[8];
  const float* bc1 = (const float*)d_in[9];
  const float* Wc2 = (const float*)d_in[10];
  const float* bc2 = (const float*)d_in[11];
  const float* Wc3 = (const float*)d_in[12];
  const float* bc3 = (const float*)d_in[13];
  float* out = (float*)d_out;

  float*  ws     = (float*)d_ws;
  int*    deg    = (int*)ws;
  float*  agg_h0 = ws + (size_t)NN;
  float*  agg_e  = ws + (size_t)3 * NN;
  float*  agg_h1 = ws + (size_t)35 * NN;
  __half* Pb     = (__half*)(ws + (size_t)35 * NN);   // aliases agg_h1 (dead)
  __half* Qb     = (__half*)(ws + (size_t)67 * NN);
  __half* h1h    = (__half*)(ws + (size_t)99 * NN);
  float*  W1t    = ws + (size_t)131 * NN;
  float*  W2t    = W1t + 4096;
  float*  WAt    = W1t + 16384;
  float*  WBt    = W1t + 20480;
  int*    bsums  = (int*)(W1t + 30000);
  int*    offs   = (int*)(ws + (size_t)132 * NN);
  int*    fill   = (int*)(ws + (size_t)133 * NN);
  int*    elist  = (int*)(ws + (size_t)134 * NN);
  int*    slist  = (int*)(ws + (size_t)150 * NN);
  float*  h2     = ws + (size_t)163 * NN;  // clobbers slist tail after gathers

  hipMemsetAsync(deg, 0, NN * sizeof(int), stream);
  hipMemsetAsync(fill, 0, NN * sizeof(int), stream);

  k_wt<<<40, 256, 0, stream>>>(W1, W2, Wc1, W1t, W2t, WAt, WBt);
  k_hist<<<(NE + 255) / 256, 256, 0, stream>>>(ei, deg);
  k_scan1<<<NB_SCAN, 256, 0, stream>>>(deg, offs, bsums);
  k_scan2<<<1, 256, 0, stream>>>(bsums);
  k_scan3<<<NB_SCAN, 256, 0, stream>>>(offs, bsums);
  k_scatter<<<(NE + 255) / 256, 256, 0, stream>>>(ei, offs, fill, elist, slist);

  k_gather0<<<(NN * 64 + 255) / 256, 256, 0, stream>>>(ea, ns, offs, deg,
                                                       elist, slist, agg_h0,
                                                       agg_e);
  k_node_lin1<<<(NN * 64 + 255) / 256, 256, 0, stream>>>(ns, deg, agg_h0,
                                                         agg_e, W1t, b1, h1h);
  k_gather1<<<(NN * 64 + 255) / 256, 256, 0, stream>>>(h1h, offs, deg, slist,
                                                       agg_h1);
  k_node_lin2<<<(NN * 64 + 255) / 256, 256, 0, stream>>>(h1h, deg, agg_h1,
                                                         agg_e, W2t, b2, h2);
  k_node_pq<<<(NN * 64 + 255) / 256, 256, 0, stream>>>(h2, WAt, WBt, bc1, Pb,
                                                       Qb);
  k_edge_cls<<<CLS_BLOCKS, 256, 0, stream>>>(ei, ea, Pb, Qb, Wc1, Wc2, bc2,
                                             Wc3, bc3, out);
}

// Round 7
// 306.942 us; speedup vs baseline: 4.7839x; 1.5527x over previous
//
#include <hip/hip_runtime.h>
#include <hip/hip_fp16.h>

#define NN 50000
#define NE 800000
#define NB_SCAN 196  // ceil(NN/256)

typedef _Float16 f16x8 __attribute__((ext_vector_type(8)));
typedef float f32x4 __attribute__((ext_vector_type(4)));
union U4 { uint4 u; f16x8 f; __half2 h2[4]; };

__device__ inline f16x8 cvt8(float4 a0, float4 a1) {
  U4 u;
  u.h2[0] = __floats2half2_rn(a0.x, a0.y);
  u.h2[1] = __floats2half2_rn(a0.z, a0.w);
  u.h2[2] = __floats2half2_rn(a1.x, a1.y);
  u.h2[3] = __floats2half2_rn(a1.z, a1.w);
  return u.f;
}

// ---- workspace layout (4B units), 227*NN floats ----
// deg i32[NN]@0 | agg_h0[2NN]@NN | agg_e[32NN]@3NN | agg_h1 f32[64NN]@35NN
// h1h f16(64NN halves = 32NN)@99NN..131NN | W1t@131NN(2304), bsums@131NN+30000
// offs@132NN fill@133NN elist@134NN..150NN slist@150NN..166NN
// Pb f16@163NN..195NN (32NN), Qb f16@195NN..227NN (32NN)
//   (Pb clobbers slist tail, which is dead after gathers; Qb ends at 227NN)

// ---------------- weight transpose: W1t[k][o] = W1[o][k] --------------------
__global__ __launch_bounds__(256) void k_wt(const float* __restrict__ W1,
                                            float* __restrict__ W1t) {
  int id = blockIdx.x * 256 + threadIdx.x;
  if (id < 36 * 64) {
    int k = id >> 6, o = id & 63;
    W1t[id] = W1[o * 36 + k];
  }
}

// ---------------- CSR build -------------------------------------------------
__global__ __launch_bounds__(256) void k_hist(const int* __restrict__ ei,
                                              int* __restrict__ deg) {
  int e = blockIdx.x * 256 + threadIdx.x;
  if (e >= NE) return;
  atomicAdd(&deg[ei[NE + e]], 1);
}

__global__ __launch_bounds__(256) void k_scan1(const int* __restrict__ deg,
                                               int* __restrict__ offs,
                                               int* __restrict__ bsums) {
  __shared__ int sh[256];
  int tid = threadIdx.x;
  int i = blockIdx.x * 256 + tid;
  int v = (i < NN) ? deg[i] : 0;
  int val = v;
  sh[tid] = val;
  __syncthreads();
  for (int ofs = 1; ofs < 256; ofs <<= 1) {
    int t = (tid >= ofs) ? sh[tid - ofs] : 0;
    __syncthreads();
    val += t;
    sh[tid] = val;
    __syncthreads();
  }
  if (i < NN) offs[i] = val - v;
  if (tid == 255) bsums[blockIdx.x] = val;
}

__global__ __launch_bounds__(256) void k_scan2(int* __restrict__ bsums) {
  __shared__ int sh[256];
  int tid = threadIdx.x;
  int v = (tid < NB_SCAN) ? bsums[tid] : 0;
  int val = v;
  sh[tid] = val;
  __syncthreads();
  for (int ofs = 1; ofs < 256; ofs <<= 1) {
    int t = (tid >= ofs) ? sh[tid - ofs] : 0;
    __syncthreads();
    val += t;
    sh[tid] = val;
    __syncthreads();
  }
  if (tid < NB_SCAN) bsums[tid] = val - v;
}

__global__ __launch_bounds__(256) void k_scan3(int* __restrict__ offs,
                                               const int* __restrict__ bsums) {
  int i = blockIdx.x * 256 + threadIdx.x;
  if (i < NN) offs[i] += bsums[blockIdx.x];
}

__global__ __launch_bounds__(256) void k_scatter(const int* __restrict__ ei,
                                                 const int* __restrict__ offs,
                                                 int* __restrict__ fill,
                                                 int* __restrict__ elist,
                                                 int* __restrict__ slist) {
  int e = blockIdx.x * 256 + threadIdx.x;
  if (e >= NE) return;
  int d = ei[NE + e];
  int pos = offs[d] + atomicAdd(&fill[d], 1);
  elist[pos] = e;
  slist[pos] = ei[e];
}

// ---------------- gathers: 4-edge unroll, independent accumulators ----------
__global__ __launch_bounds__(256) void k_gather0(
    const float* __restrict__ ea, const float* __restrict__ ns,
    const int* __restrict__ offs, const int* __restrict__ deg,
    const int* __restrict__ elist, const int* __restrict__ slist,
    float* __restrict__ agg_h0, float* __restrict__ agg_e) {
  int idx = blockIdx.x * 256 + threadIdx.x;
  int n = idx >> 6, lane = idx & 63;
  if (n >= NN) return;
  int off = offs[n], dg = deg[n];
  int k = lane & 31, half = lane >> 5;
  float acc = 0.f, acc2 = 0.f, acch = 0.f, acch2 = 0.f;
  int i = 0;
#pragma unroll 2
  for (; i + 4 <= dg; i += 4) {
    int eA = elist[off + i + half];
    int eB = elist[off + i + 2 + half];
    int sA = slist[off + i + half];
    int sB = slist[off + i + 2 + half];
    acc += ea[(size_t)eA * 32 + k];
    acc2 += ea[(size_t)eB * 32 + k];
    if (k < 2) {
      acch += ns[(size_t)sA * 2 + k];
      acch2 += ns[(size_t)sB * 2 + k];
    }
  }
  for (; i + 2 <= dg; i += 2) {
    int e = elist[off + i + half];
    acc += ea[(size_t)e * 32 + k];
    if (k < 2) acch += ns[(size_t)slist[off + i + half] * 2 + k];
  }
  if (i < dg && half == 0) {
    int e = elist[off + i];
    acc += ea[(size_t)e * 32 + k];
    if (k < 2) acch += ns[(size_t)slist[off + i] * 2 + k];
  }
  acc += acc2;
  acch += acch2;
  acc += __shfl_xor(acc, 32);
  acch += __shfl_xor(acch, 32);
  if (lane < 32) agg_e[n * 32 + lane] = acc;
  if (lane < 2) agg_h0[n * 2 + lane] = acch;
}

__global__ __launch_bounds__(256) void k_gather1(
    const __half* __restrict__ h1h, const int* __restrict__ offs,
    const int* __restrict__ deg, const int* __restrict__ slist,
    float* __restrict__ agg_h1) {
  int idx = blockIdx.x * 256 + threadIdx.x;
  int n = idx >> 6, lane = idx & 63;
  if (n >= NN) return;
  int off = offs[n], dg = deg[n];
  float acc = 0.f, acc2 = 0.f;
  int i = 0;
#pragma unroll 2
  for (; i + 4 <= dg; i += 4) {
    int s0 = slist[off + i], s1 = slist[off + i + 1];
    int s2 = slist[off + i + 2], s3 = slist[off + i + 3];
    float a = __half2float(h1h[(size_t)s0 * 64 + lane]);
    float b = __half2float(h1h[(size_t)s1 * 64 + lane]);
    float c = __half2float(h1h[(size_t)s2 * 64 + lane]);
    float d = __half2float(h1h[(size_t)s3 * 64 + lane]);
    acc += a + b;
    acc2 += c + d;
  }
  for (; i < dg; ++i)
    acc += __half2float(h1h[(size_t)slist[off + i] * 64 + lane]);
  agg_h1[(size_t)n * 64 + lane] = acc + acc2;
}

// ---------------- node linear 1 (vector; K=36) ------------------------------
__global__ __launch_bounds__(256) void k_node_lin1(
    const float* __restrict__ ns, const int* __restrict__ deg,
    const float* __restrict__ agg_h0, const float* __restrict__ agg_e,
    const float* __restrict__ W1t, const float* __restrict__ b1,
    __half* __restrict__ h1h) {
  int idx = blockIdx.x * 256 + threadIdx.x;
  int n = idx >> 6, o = idx & 63;
  if (n >= NN) return;
  float inv = 1.0f / fmaxf((float)deg[n], 1.0f);
  float acc = b1[o], acc2 = 0.f;
  acc += ns[n * 2 + 0] * W1t[0 * 64 + o] + ns[n * 2 + 1] * W1t[1 * 64 + o];
  acc2 += agg_h0[n * 2 + 0] * inv * W1t[2 * 64 + o] +
          agg_h0[n * 2 + 1] * inv * W1t[3 * 64 + o];
#pragma unroll
  for (int k = 0; k < 32; k += 2) {
    acc += agg_e[n * 32 + k] * inv * W1t[(4 + k) * 64 + o];
    acc2 += agg_e[n * 32 + k + 1] * inv * W1t[(5 + k) * 64 + o];
  }
  h1h[n * 64 + o] = __float2half(fmaxf(acc + acc2, 0.0f));
}

// ---------------- fused lin2 + pq: MFMA, 16-node tile per wave --------------
// stage1: h2[16][64] = relu(f16(concat(h1,agg_h1*inv,agg_e*inv)) @ W2^T + b2)
// stage2: P = h2 @ WA^T + bc1 ; Q = h2 @ WB^T  (WA/WB = col-slices of Wc1)
// B-frags read directly from row-major W2/Wc1 ([o][k] = B^T fragment order).
__global__ __launch_bounds__(256) void k_lin2pq(
    const __half* __restrict__ h1h, const int* __restrict__ deg,
    const float* __restrict__ agg_h1, const float* __restrict__ agg_e,
    const float* __restrict__ W2, const float* __restrict__ b2,
    const float* __restrict__ Wc1, const float* __restrict__ bc1,
    __half* __restrict__ Pb, __half* __restrict__ Qb) {
  __shared__ float Zt[4][16 * 68];
  int tid = threadIdx.x, lane = tid & 63, wid = tid >> 6;
  int col = lane & 15, quad = lane >> 4;
  float* zl = &Zt[wid][0];
  int task = blockIdx.x * 4 + wid;
  if (task >= NN / 16) return;  // NN = 3125*16 exactly
  int nb = task * 16;
  int nrow = nb + col;
  float inv = 1.0f / fmaxf((float)deg[nrow], 1.0f);

  f32x4 zero = {0.f, 0.f, 0.f, 0.f};
  f32x4 ce[4] = {zero, zero, zero, zero};

#pragma unroll
  for (int kc = 0; kc < 5; ++kc) {
    f16x8 af;
    if (kc < 2) {
      U4 u;
      u.u = *(const uint4*)(h1h + (size_t)nrow * 64 + kc * 32 + quad * 8);
      af = u.f;
    } else if (kc < 4) {
      const float* p = agg_h1 + (size_t)nrow * 64 + (kc - 2) * 32 + quad * 8;
      float4 a0 = ((const float4*)p)[0], a1 = ((const float4*)p)[1];
      a0.x *= inv; a0.y *= inv; a0.z *= inv; a0.w *= inv;
      a1.x *= inv; a1.y *= inv; a1.z *= inv; a1.w *= inv;
      af = cvt8(a0, a1);
    } else {
      const float* p = agg_e + (size_t)nrow * 32 + quad * 8;
      float4 a0 = ((const float4*)p)[0], a1 = ((const float4*)p)[1];
      a0.x *= inv; a0.y *= inv; a0.z *= inv; a0.w *= inv;
      a1.x *= inv; a1.y *= inv; a1.z *= inv; a1.w *= inv;
      af = cvt8(a0, a1);
    }
#pragma unroll
    for (int ob = 0; ob < 4; ++ob) {
      const float* wp = W2 + (size_t)(ob * 16 + col) * 160 + kc * 32 + quad * 8;
      f16x8 bf = cvt8(((const float4*)wp)[0], ((const float4*)wp)[1]);
      ce[ob] = __builtin_amdgcn_mfma_f32_16x16x32_f16(af, bf, ce[ob], 0, 0, 0);
    }
  }
  // bias + relu + scatter C-frags to wave-private LDS tile [node][o]
#pragma unroll
  for (int ob = 0; ob < 4; ++ob) {
    float bv = b2[ob * 16 + col];
#pragma unroll
    for (int j = 0; j < 4; ++j)
      zl[(quad * 4 + j) * 68 + ob * 16 + col] = fmaxf(ce[ob][j] + bv, 0.f);
  }

  f32x4 pacc[4] = {zero, zero, zero, zero};
  f32x4 qacc[4] = {zero, zero, zero, zero};
#pragma unroll
  for (int kc = 0; kc < 2; ++kc) {
    const float* zc = zl + col * 68 + kc * 32 + quad * 8;
    f16x8 az = cvt8(((const float4*)zc)[0], ((const float4*)zc)[1]);
#pragma unroll
    for (int ob = 0; ob < 4; ++ob) {
      const float* wa = Wc1 + (size_t)(ob * 16 + col) * 160 + kc * 32 + quad * 8;
      f16x8 ba = cvt8(((const float4*)wa)[0], ((const float4*)wa)[1]);
      pacc[ob] = __builtin_amdgcn_mfma_f32_16x16x32_f16(az, ba, pacc[ob], 0, 0, 0);
      const float* wb = wa + 64;
      f16x8 bb = cvt8(((const float4*)wb)[0], ((const float4*)wb)[1]);
      qacc[ob] = __builtin_amdgcn_mfma_f32_16x16x32_f16(az, bb, qacc[ob], 0, 0, 0);
    }
  }
  // D[m = quad*4+j][o = ob*16+col] -> Pb/Qb rows nb+m
#pragma unroll
  for (int ob = 0; ob < 4; ++ob) {
    float bv = bc1[ob * 16 + col];
#pragma unroll
    for (int j = 0; j < 4; ++j) {
      int n = nb + quad * 4 + j;
      Pb[(size_t)n * 64 + ob * 16 + col] = __float2half(pacc[ob][j] + bv);
      Qb[(size_t)n * 64 + ob * 16 + col] = __float2half(qacc[ob][j]);
    }
  }
}

// ---------------- edge classifier: MFMA (verified R4 structure) -------------
#define CLS_BLOCKS 1563
__global__ __launch_bounds__(256) void k_edge_cls(
    const int* __restrict__ ei, const float* __restrict__ ea,
    const __half* __restrict__ Pb, const __half* __restrict__ Qb,
    const float* __restrict__ Wc1, const float* __restrict__ Wc2,
    const float* __restrict__ bc2, const float* __restrict__ Wc3,
    const float* __restrict__ bc3, float* __restrict__ out) {
  __shared__ float Zt[4][16 * 68];
  int tid = threadIdx.x;
  int lane = tid & 63, wid = tid >> 6;
  int col = lane & 15, quad = lane >> 4;
  float* zl = &Zt[wid][0];

  f16x8 ctF[4];
#pragma unroll
  for (int nt = 0; nt < 4; ++nt) {
    const float* p = Wc1 + (nt * 16 + col) * 160 + 128 + quad * 8;
    ctF[nt] = cvt8(((const float4*)p)[0], ((const float4*)p)[1]);
  }
  f16x8 w2F[2][2];
#pragma unroll
  for (int nt = 0; nt < 2; ++nt)
#pragma unroll
    for (int ks = 0; ks < 2; ++ks) {
      const float* p = Wc2 + (nt * 16 + col) * 64 + ks * 32 + quad * 8;
      w2F[nt][ks] = cvt8(((const float4*)p)[0], ((const float4*)p)[1]);
    }
  float wc3v0 = Wc3[col], wc3v1 = Wc3[16 + col];
  float bc2v0 = bc2[col], bc2v1 = bc2[16 + col];
  float bc3v = bc3[0];

  int gw = blockIdx.x * 4 + wid;
  for (int task = gw; task < NE / 64; task += CLS_BLOCKS * 4) {
    int tb = task * 64;
#pragma unroll
    for (int mt = 0; mt < 4; ++mt) {
      int eb = tb + mt * 16;
      int e = eb + col;
      int s = ei[e], d = ei[NE + e];

      const float* eap = ea + (size_t)e * 32 + quad * 8;
      f16x8 ua = cvt8(((const float4*)eap)[0], ((const float4*)eap)[1]);
      f32x4 zero = {0.f, 0.f, 0.f, 0.f};
      f32x4 ce[4];
#pragma unroll
      for (int nt = 0; nt < 4; ++nt)
        ce[nt] = __builtin_amdgcn_mfma_f32_16x16x32_f16(ua, ctF[nt], zero,
                                                        0, 0, 0);
#pragma unroll
      for (int nt = 0; nt < 4; ++nt)
#pragma unroll
        for (int j = 0; j < 4; ++j)
          zl[(quad * 4 + j) * 68 + nt * 16 + col] = ce[nt][j];

      const __half* prow = Pb + (size_t)s * 64 + quad * 8;
      const __half* qrow = Qb + (size_t)d * 64 + quad * 8;
      f32x4 tacc0 = zero, tacc1 = zero;
#pragma unroll
      for (int ks = 0; ks < 2; ++ks) {
        U4 up, uq;
        up.u = *(const uint4*)(prow + ks * 32);
        uq.u = *(const uint4*)(qrow + ks * 32);
        const float* zc = zl + col * 68 + ks * 32 + quad * 8;
        float4 c0 = *(const float4*)(zc);
        float4 c1 = *(const float4*)(zc + 4);
        U4 uz;
        {
          float2 pf, qf;
          pf = __half22float2(up.h2[0]); qf = __half22float2(uq.h2[0]);
          uz.h2[0] = __floats2half2_rn(fmaxf(pf.x + qf.x + c0.x, 0.f),
                                       fmaxf(pf.y + qf.y + c0.y, 0.f));
          pf = __half22float2(up.h2[1]); qf = __half22float2(uq.h2[1]);
          uz.h2[1] = __floats2half2_rn(fmaxf(pf.x + qf.x + c0.z, 0.f),
                                       fmaxf(pf.y + qf.y + c0.w, 0.f));
          pf = __half22float2(up.h2[2]); qf = __half22float2(uq.h2[2]);
          uz.h2[2] = __floats2half2_rn(fmaxf(pf.x + qf.x + c1.x, 0.f),
                                       fmaxf(pf.y + qf.y + c1.y, 0.f));
          pf = __half22float2(up.h2[3]); qf = __half22float2(uq.h2[3]);
          uz.h2[3] = __floats2half2_rn(fmaxf(pf.x + qf.x + c1.z, 0.f),
                                       fmaxf(pf.y + qf.y + c1.w, 0.f));
        }
        tacc0 = __builtin_amdgcn_mfma_f32_16x16x32_f16(uz.f, w2F[0][ks],
                                                       tacc0, 0, 0, 0);
        tacc1 = __builtin_amdgcn_mfma_f32_16x16x32_f16(uz.f, w2F[1][ks],
                                                       tacc1, 0, 0, 0);
      }

      float vj[4];
#pragma unroll
      for (int j = 0; j < 4; ++j) {
        float t0 = fmaxf(tacc0[j] + bc2v0, 0.f);
        float t1 = fmaxf(tacc1[j] + bc2v1, 0.f);
        vj[j] = t0 * wc3v0 + t1 * wc3v1;
      }
#pragma unroll
      for (int m = 1; m < 16; m <<= 1) {
#pragma unroll
        for (int j = 0; j < 4; ++j) vj[j] += __shfl_xor(vj[j], m);
      }
      if (col == 0) {
#pragma unroll
        for (int j = 0; j < 4; ++j) out[eb + quad * 4 + j] = vj[j] + bc3v;
      }
    }
  }
}

extern "C" void kernel_launch(void* const* d_in, const int* in_sizes, int n_in,
                              void* d_out, int out_size, void* d_ws, size_t ws_size,
                              hipStream_t stream) {
  const int*   ei  = (const int*)d_in[1];
  const float* ea  = (const float*)d_in[2];
  const float* ns  = (const float*)d_in[3];
  const float* W1  = (const float*)d_in[4];
  const float* b1  = (const float*)d_in[5];
  const float* W2  = (const float*)d_in[6];
  const float* b2  = (const float*)d_in[7];
  const float* Wc1 = (const float*)d_in[8];
  const float* bc1 = (const float*)d_in[9];
  const float* Wc2 = (const float*)d_in[10];
  const float* bc2 = (const float*)d_in[11];
  const float* Wc3 = (const float*)d_in[12];
  const float* bc3 = (const float*)d_in[13];
  float* out = (float*)d_out;

  float*  ws     = (float*)d_ws;
  int*    deg    = (int*)ws;
  float*  agg_h0 = ws + (size_t)NN;
  float*  agg_e  = ws + (size_t)3 * NN;
  float*  agg_h1 = ws + (size_t)35 * NN;
  __half* h1h    = (__half*)(ws + (size_t)99 * NN);
  float*  W1t    = ws + (size_t)131 * NN;
  int*    bsums  = (int*)(W1t + 30000);
  int*    offs   = (int*)(ws + (size_t)132 * NN);
  int*    fill   = (int*)(ws + (size_t)133 * NN);
  int*    elist  = (int*)(ws + (size_t)134 * NN);
  int*    slist  = (int*)(ws + (size_t)150 * NN);
  __half* Pb     = (__half*)(ws + (size_t)163 * NN);  // 32NN units, ends 195NN
  __half* Qb     = (__half*)(ws + (size_t)195 * NN);  // 32NN units, ends 227NN

  hipMemsetAsync(deg, 0, NN * sizeof(int), stream);
  hipMemsetAsync(fill, 0, NN * sizeof(int), stream);

  k_wt<<<9, 256, 0, stream>>>(W1, W1t);
  k_hist<<<(NE + 255) / 256, 256, 0, stream>>>(ei, deg);
  k_scan1<<<NB_SCAN, 256, 0, stream>>>(deg, offs, bsums);
  k_scan2<<<1, 256, 0, stream>>>(bsums);
  k_scan3<<<NB_SCAN, 256, 0, stream>>>(offs, bsums);
  k_scatter<<<(NE + 255) / 256, 256, 0, stream>>>(ei, offs, fill, elist, slist);

  k_gather0<<<(NN * 64 + 255) / 256, 256, 0, stream>>>(ea, ns, offs, deg,
                                                       elist, slist, agg_h0,
                                                       agg_e);
  k_node_lin1<<<(NN * 64 + 255) / 256, 256, 0, stream>>>(ns, deg, agg_h0,
                                                         agg_e, W1t, b1, h1h);
  k_gather1<<<(NN * 64 + 255) / 256, 256, 0, stream>>>(h1h, offs, deg, slist,
                                                       agg_h1);
  k_lin2pq<<<(NN / 16 + 3) / 4, 256, 0, stream>>>(h1h, deg, agg_h1, agg_e, W2,
                                                  b2, Wc1, bc1, Pb, Qb);
  k_edge_cls<<<CLS_BLOCKS, 256, 0, stream>>>(ei, ea, Pb, Qb, Wc1, Wc2, bc2,
                                             Wc3, bc3, out);
}

// Round 8
// 306.635 us; speedup vs baseline: 4.7887x; 1.0010x over previous
//
#include <hip/hip_runtime.h>
#include <hip/hip_fp16.h>

#define NN 50000
#define NE 800000
#define NB_SCAN 196  // ceil(NN/256)

typedef _Float16 f16x8 __attribute__((ext_vector_type(8)));
typedef float f32x4 __attribute__((ext_vector_type(4)));
union U4 { uint4 u; f16x8 f; __half2 h2[4]; };

__device__ inline f16x8 cvt8(float4 a0, float4 a1) {
  U4 u;
  u.h2[0] = __floats2half2_rn(a0.x, a0.y);
  u.h2[1] = __floats2half2_rn(a0.z, a0.w);
  u.h2[2] = __floats2half2_rn(a1.x, a1.y);
  u.h2[3] = __floats2half2_rn(a1.z, a1.w);
  return u.f;
}

// ---- workspace layout (4B units), 227*NN floats ----
// deg i32[NN]@0 | agg_h0[2NN]@NN | agg_e[32NN]@3NN | agg_h1 f32[64NN]@35NN
// h1h f16(64NN halves = 32NN)@99NN..131NN | W1t@131NN(2304), bsums@131NN+30000
// offs@132NN fill@133NN elist@134NN..150NN slist@150NN..166NN
// Pb f16@163NN..195NN (32NN), Qb f16@195NN..227NN (32NN)
//   (Pb clobbers slist tail, which is dead after gathers; Qb ends at 227NN)

// ---------------- weight transpose: W1t[k][o] = W1[o][k] --------------------
__global__ __launch_bounds__(256) void k_wt(const float* __restrict__ W1,
                                            float* __restrict__ W1t) {
  int id = blockIdx.x * 256 + threadIdx.x;
  if (id < 36 * 64) {
    int k = id >> 6, o = id & 63;
    W1t[id] = W1[o * 36 + k];
  }
}

// ---------------- CSR build -------------------------------------------------
__global__ __launch_bounds__(256) void k_hist(const int* __restrict__ ei,
                                              int* __restrict__ deg) {
  int e = blockIdx.x * 256 + threadIdx.x;
  if (e >= NE) return;
  atomicAdd(&deg[ei[NE + e]], 1);
}

__global__ __launch_bounds__(256) void k_scan1(const int* __restrict__ deg,
                                               int* __restrict__ offs,
                                               int* __restrict__ bsums) {
  __shared__ int sh[256];
  int tid = threadIdx.x;
  int i = blockIdx.x * 256 + tid;
  int v = (i < NN) ? deg[i] : 0;
  int val = v;
  sh[tid] = val;
  __syncthreads();
  for (int ofs = 1; ofs < 256; ofs <<= 1) {
    int t = (tid >= ofs) ? sh[tid - ofs] : 0;
    __syncthreads();
    val += t;
    sh[tid] = val;
    __syncthreads();
  }
  if (i < NN) offs[i] = val - v;
  if (tid == 255) bsums[blockIdx.x] = val;
}

__global__ __launch_bounds__(256) void k_scan2(int* __restrict__ bsums) {
  __shared__ int sh[256];
  int tid = threadIdx.x;
  int v = (tid < NB_SCAN) ? bsums[tid] : 0;
  int val = v;
  sh[tid] = val;
  __syncthreads();
  for (int ofs = 1; ofs < 256; ofs <<= 1) {
    int t = (tid >= ofs) ? sh[tid - ofs] : 0;
    __syncthreads();
    val += t;
    sh[tid] = val;
    __syncthreads();
  }
  if (tid < NB_SCAN) bsums[tid] = val - v;
}

__global__ __launch_bounds__(256) void k_scan3(int* __restrict__ offs,
                                               const int* __restrict__ bsums) {
  int i = blockIdx.x * 256 + threadIdx.x;
  if (i < NN) offs[i] += bsums[blockIdx.x];
}

__global__ __launch_bounds__(256) void k_scatter(const int* __restrict__ ei,
                                                 const int* __restrict__ offs,
                                                 int* __restrict__ fill,
                                                 int* __restrict__ elist,
                                                 int* __restrict__ slist) {
  int e = blockIdx.x * 256 + threadIdx.x;
  if (e >= NE) return;
  int d = ei[NE + e];
  int pos = offs[d] + atomicAdd(&fill[d], 1);
  elist[pos] = e;
  slist[pos] = ei[e];
}

// ---------------- gather0: 32 lanes/node, 8-edge unroll ---------------------
// 8 broadcast elist loads up front -> 8 independent 128B ea rows in flight.
__global__ __launch_bounds__(256) void k_gather0(
    const float* __restrict__ ea, const float* __restrict__ ns,
    const int* __restrict__ offs, const int* __restrict__ deg,
    const int* __restrict__ elist, const int* __restrict__ slist,
    float* __restrict__ agg_h0, float* __restrict__ agg_e) {
  int idx = blockIdx.x * 256 + threadIdx.x;
  int n = idx >> 5, k = idx & 31;
  if (n >= NN) return;
  int off = offs[n], dg = deg[n];
  float a0 = 0.f, a1 = 0.f, a2 = 0.f, a3 = 0.f;
  float h0 = 0.f, h1v = 0.f;
  int i = 0;
  for (; i + 8 <= dg; i += 8) {
    int e0 = elist[off + i + 0], e1 = elist[off + i + 1];
    int e2 = elist[off + i + 2], e3 = elist[off + i + 3];
    int e4 = elist[off + i + 4], e5 = elist[off + i + 5];
    int e6 = elist[off + i + 6], e7 = elist[off + i + 7];
    a0 += ea[(size_t)e0 * 32 + k];
    a1 += ea[(size_t)e1 * 32 + k];
    a2 += ea[(size_t)e2 * 32 + k];
    a3 += ea[(size_t)e3 * 32 + k];
    a0 += ea[(size_t)e4 * 32 + k];
    a1 += ea[(size_t)e5 * 32 + k];
    a2 += ea[(size_t)e6 * 32 + k];
    a3 += ea[(size_t)e7 * 32 + k];
    if (k < 2) {
      int s0 = slist[off + i + 0], s1 = slist[off + i + 1];
      int s2 = slist[off + i + 2], s3 = slist[off + i + 3];
      int s4 = slist[off + i + 4], s5 = slist[off + i + 5];
      int s6 = slist[off + i + 6], s7 = slist[off + i + 7];
      h0 += ns[(size_t)s0 * 2 + k] + ns[(size_t)s2 * 2 + k];
      h1v += ns[(size_t)s1 * 2 + k] + ns[(size_t)s3 * 2 + k];
      h0 += ns[(size_t)s4 * 2 + k] + ns[(size_t)s6 * 2 + k];
      h1v += ns[(size_t)s5 * 2 + k] + ns[(size_t)s7 * 2 + k];
    }
  }
  for (; i + 2 <= dg; i += 2) {
    int e0 = elist[off + i], e1 = elist[off + i + 1];
    a0 += ea[(size_t)e0 * 32 + k];
    a1 += ea[(size_t)e1 * 32 + k];
    if (k < 2) {
      h0 += ns[(size_t)slist[off + i] * 2 + k];
      h1v += ns[(size_t)slist[off + i + 1] * 2 + k];
    }
  }
  if (i < dg) {
    a0 += ea[(size_t)elist[off + i] * 32 + k];
    if (k < 2) h0 += ns[(size_t)slist[off + i] * 2 + k];
  }
  agg_e[(size_t)n * 32 + k] = (a0 + a1) + (a2 + a3);
  if (k < 2) agg_h0[(size_t)n * 2 + k] = h0 + h1v;
}

// ---------------- gather1: wave/node, 8-row unroll --------------------------
__global__ __launch_bounds__(256) void k_gather1(
    const __half* __restrict__ h1h, const int* __restrict__ offs,
    const int* __restrict__ deg, const int* __restrict__ slist,
    float* __restrict__ agg_h1) {
  int idx = blockIdx.x * 256 + threadIdx.x;
  int n = idx >> 6, lane = idx & 63;
  if (n >= NN) return;
  int off = offs[n], dg = deg[n];
  float a0 = 0.f, a1 = 0.f, a2 = 0.f, a3 = 0.f;
  int i = 0;
  for (; i + 8 <= dg; i += 8) {
    int s0 = slist[off + i + 0], s1 = slist[off + i + 1];
    int s2 = slist[off + i + 2], s3 = slist[off + i + 3];
    int s4 = slist[off + i + 4], s5 = slist[off + i + 5];
    int s6 = slist[off + i + 6], s7 = slist[off + i + 7];
    a0 += __half2float(h1h[(size_t)s0 * 64 + lane]);
    a1 += __half2float(h1h[(size_t)s1 * 64 + lane]);
    a2 += __half2float(h1h[(size_t)s2 * 64 + lane]);
    a3 += __half2float(h1h[(size_t)s3 * 64 + lane]);
    a0 += __half2float(h1h[(size_t)s4 * 64 + lane]);
    a1 += __half2float(h1h[(size_t)s5 * 64 + lane]);
    a2 += __half2float(h1h[(size_t)s6 * 64 + lane]);
    a3 += __half2float(h1h[(size_t)s7 * 64 + lane]);
  }
  for (; i + 2 <= dg; i += 2) {
    int s0 = slist[off + i], s1 = slist[off + i + 1];
    a0 += __half2float(h1h[(size_t)s0 * 64 + lane]);
    a1 += __half2float(h1h[(size_t)s1 * 64 + lane]);
  }
  if (i < dg) a0 += __half2float(h1h[(size_t)slist[off + i] * 64 + lane]);
  agg_h1[(size_t)n * 64 + lane] = (a0 + a1) + (a2 + a3);
}

// ---------------- node linear 1 (vector; K=36) ------------------------------
__global__ __launch_bounds__(256) void k_node_lin1(
    const float* __restrict__ ns, const int* __restrict__ deg,
    const float* __restrict__ agg_h0, const float* __restrict__ agg_e,
    const float* __restrict__ W1t, const float* __restrict__ b1,
    __half* __restrict__ h1h) {
  int idx = blockIdx.x * 256 + threadIdx.x;
  int n = idx >> 6, o = idx & 63;
  if (n >= NN) return;
  float inv = 1.0f / fmaxf((float)deg[n], 1.0f);
  float acc = b1[o], acc2 = 0.f;
  acc += ns[n * 2 + 0] * W1t[0 * 64 + o] + ns[n * 2 + 1] * W1t[1 * 64 + o];
  acc2 += agg_h0[n * 2 + 0] * inv * W1t[2 * 64 + o] +
          agg_h0[n * 2 + 1] * inv * W1t[3 * 64 + o];
#pragma unroll
  for (int k = 0; k < 32; k += 2) {
    acc += agg_e[n * 32 + k] * inv * W1t[(4 + k) * 64 + o];
    acc2 += agg_e[n * 32 + k + 1] * inv * W1t[(5 + k) * 64 + o];
  }
  h1h[n * 64 + o] = __float2half(fmaxf(acc + acc2, 0.0f));
}

// ---------------- fused lin2 + pq: MFMA, 16-node tile per wave --------------
__global__ __launch_bounds__(256) void k_lin2pq(
    const __half* __restrict__ h1h, const int* __restrict__ deg,
    const float* __restrict__ agg_h1, const float* __restrict__ agg_e,
    const float* __restrict__ W2, const float* __restrict__ b2,
    const float* __restrict__ Wc1, const float* __restrict__ bc1,
    __half* __restrict__ Pb, __half* __restrict__ Qb) {
  __shared__ float Zt[4][16 * 68];
  int tid = threadIdx.x, lane = tid & 63, wid = tid >> 6;
  int col = lane & 15, quad = lane >> 4;
  float* zl = &Zt[wid][0];
  int task = blockIdx.x * 4 + wid;
  if (task >= NN / 16) return;  // NN = 3125*16 exactly
  int nb = task * 16;
  int nrow = nb + col;
  float inv = 1.0f / fmaxf((float)deg[nrow], 1.0f);

  f32x4 zero = {0.f, 0.f, 0.f, 0.f};
  f32x4 ce[4] = {zero, zero, zero, zero};

#pragma unroll
  for (int kc = 0; kc < 5; ++kc) {
    f16x8 af;
    if (kc < 2) {
      U4 u;
      u.u = *(const uint4*)(h1h + (size_t)nrow * 64 + kc * 32 + quad * 8);
      af = u.f;
    } else if (kc < 4) {
      const float* p = agg_h1 + (size_t)nrow * 64 + (kc - 2) * 32 + quad * 8;
      float4 a0 = ((const float4*)p)[0], a1 = ((const float4*)p)[1];
      a0.x *= inv; a0.y *= inv; a0.z *= inv; a0.w *= inv;
      a1.x *= inv; a1.y *= inv; a1.z *= inv; a1.w *= inv;
      af = cvt8(a0, a1);
    } else {
      const float* p = agg_e + (size_t)nrow * 32 + quad * 8;
      float4 a0 = ((const float4*)p)[0], a1 = ((const float4*)p)[1];
      a0.x *= inv; a0.y *= inv; a0.z *= inv; a0.w *= inv;
      a1.x *= inv; a1.y *= inv; a1.z *= inv; a1.w *= inv;
      af = cvt8(a0, a1);
    }
#pragma unroll
    for (int ob = 0; ob < 4; ++ob) {
      const float* wp = W2 + (size_t)(ob * 16 + col) * 160 + kc * 32 + quad * 8;
      f16x8 bf = cvt8(((const float4*)wp)[0], ((const float4*)wp)[1]);
      ce[ob] = __builtin_amdgcn_mfma_f32_16x16x32_f16(af, bf, ce[ob], 0, 0, 0);
    }
  }
#pragma unroll
  for (int ob = 0; ob < 4; ++ob) {
    float bv = b2[ob * 16 + col];
#pragma unroll
    for (int j = 0; j < 4; ++j)
      zl[(quad * 4 + j) * 68 + ob * 16 + col] = fmaxf(ce[ob][j] + bv, 0.f);
  }

  f32x4 pacc[4] = {zero, zero, zero, zero};
  f32x4 qacc[4] = {zero, zero, zero, zero};
#pragma unroll
  for (int kc = 0; kc < 2; ++kc) {
    const float* zc = zl + col * 68 + kc * 32 + quad * 8;
    f16x8 az = cvt8(((const float4*)zc)[0], ((const float4*)zc)[1]);
#pragma unroll
    for (int ob = 0; ob < 4; ++ob) {
      const float* wa = Wc1 + (size_t)(ob * 16 + col) * 160 + kc * 32 + quad * 8;
      f16x8 ba = cvt8(((const float4*)wa)[0], ((const float4*)wa)[1]);
      pacc[ob] = __builtin_amdgcn_mfma_f32_16x16x32_f16(az, ba, pacc[ob], 0, 0, 0);
      const float* wb = wa + 64;
      f16x8 bb = cvt8(((const float4*)wb)[0], ((const float4*)wb)[1]);
      qacc[ob] = __builtin_amdgcn_mfma_f32_16x16x32_f16(az, bb, qacc[ob], 0, 0, 0);
    }
  }
#pragma unroll
  for (int ob = 0; ob < 4; ++ob) {
    float bv = bc1[ob * 16 + col];
#pragma unroll
    for (int j = 0; j < 4; ++j) {
      int n = nb + quad * 4 + j;
      Pb[(size_t)n * 64 + ob * 16 + col] = __float2half(pacc[ob][j] + bv);
      Qb[(size_t)n * 64 + ob * 16 + col] = __float2half(qacc[ob][j]);
    }
  }
}

// ---------------- edge classifier: MFMA, hoisted ei, dbuf LDS ---------------
#define CLS_BLOCKS 3125  // 12500 waves, 1 task (64 edges) each
__global__ __launch_bounds__(256) void k_edge_cls(
    const int* __restrict__ ei, const float* __restrict__ ea,
    const __half* __restrict__ Pb, const __half* __restrict__ Qb,
    const float* __restrict__ Wc1, const float* __restrict__ Wc2,
    const float* __restrict__ bc2, const float* __restrict__ Wc3,
    const float* __restrict__ bc3, float* __restrict__ out) {
  __shared__ float Zt[4][2][16 * 68];  // double-buffered per-wave tile
  int tid = threadIdx.x;
  int lane = tid & 63, wid = tid >> 6;
  int col = lane & 15, quad = lane >> 4;

  f16x8 ctF[4];
#pragma unroll
  for (int nt = 0; nt < 4; ++nt) {
    const float* p = Wc1 + (nt * 16 + col) * 160 + 128 + quad * 8;
    ctF[nt] = cvt8(((const float4*)p)[0], ((const float4*)p)[1]);
  }
  f16x8 w2F[2][2];
#pragma unroll
  for (int nt = 0; nt < 2; ++nt)
#pragma unroll
    for (int ks = 0; ks < 2; ++ks) {
      const float* p = Wc2 + (nt * 16 + col) * 64 + ks * 32 + quad * 8;
      w2F[nt][ks] = cvt8(((const float4*)p)[0], ((const float4*)p)[1]);
    }
  float wc3v0 = Wc3[col], wc3v1 = Wc3[16 + col];
  float bc2v0 = bc2[col], bc2v1 = bc2[16 + col];
  float bc3v = bc3[0];

  int gw = blockIdx.x * 4 + wid;
  for (int task = gw; task < NE / 64; task += CLS_BLOCKS * 4) {
    int tb = task * 64;
    // hoist all 4 tiles' edge-index loads: 8 independent loads in flight
    int sArr[4], dArr[4];
#pragma unroll
    for (int mt = 0; mt < 4; ++mt) {
      sArr[mt] = ei[tb + mt * 16 + col];
      dArr[mt] = ei[NE + tb + mt * 16 + col];
    }
#pragma unroll
    for (int mt = 0; mt < 4; ++mt) {
      int eb = tb + mt * 16;
      int e = eb + col;
      int s = sArr[mt], d = dArr[mt];
      float* zl = &Zt[wid][mt & 1][0];

      const float* eap = ea + (size_t)e * 32 + quad * 8;
      f16x8 ua = cvt8(((const float4*)eap)[0], ((const float4*)eap)[1]);
      f32x4 zero = {0.f, 0.f, 0.f, 0.f};
      f32x4 ce[4];
#pragma unroll
      for (int nt = 0; nt < 4; ++nt)
        ce[nt] = __builtin_amdgcn_mfma_f32_16x16x32_f16(ua, ctF[nt], zero,
                                                        0, 0, 0);
#pragma unroll
      for (int nt = 0; nt < 4; ++nt)
#pragma unroll
        for (int j = 0; j < 4; ++j)
          zl[(quad * 4 + j) * 68 + nt * 16 + col] = ce[nt][j];

      const __half* prow = Pb + (size_t)s * 64 + quad * 8;
      const __half* qrow = Qb + (size_t)d * 64 + quad * 8;
      f32x4 tacc0 = zero, tacc1 = zero;
#pragma unroll
      for (int ks = 0; ks < 2; ++ks) {
        U4 up, uq;
        up.u = *(const uint4*)(prow + ks * 32);
        uq.u = *(const uint4*)(qrow + ks * 32);
        const float* zc = zl + col * 68 + ks * 32 + quad * 8;
        float4 c0 = *(const float4*)(zc);
        float4 c1 = *(const float4*)(zc + 4);
        U4 uz;
        {
          float2 pf, qf;
          pf = __half22float2(up.h2[0]); qf = __half22float2(uq.h2[0]);
          uz.h2[0] = __floats2half2_rn(fmaxf(pf.x + qf.x + c0.x, 0.f),
                                       fmaxf(pf.y + qf.y + c0.y, 0.f));
          pf = __half22float2(up.h2[1]); qf = __half22float2(uq.h2[1]);
          uz.h2[1] = __floats2half2_rn(fmaxf(pf.x + qf.x + c0.z, 0.f),
                                       fmaxf(pf.y + qf.y + c0.w, 0.f));
          pf = __half22float2(up.h2[2]); qf = __half22float2(uq.h2[2]);
          uz.h2[2] = __floats2half2_rn(fmaxf(pf.x + qf.x + c1.x, 0.f),
                                       fmaxf(pf.y + qf.y + c1.y, 0.f));
          pf = __half22float2(up.h2[3]); qf = __half22float2(uq.h2[3]);
          uz.h2[3] = __floats2half2_rn(fmaxf(pf.x + qf.x + c1.z, 0.f),
                                       fmaxf(pf.y + qf.y + c1.w, 0.f));
        }
        tacc0 = __builtin_amdgcn_mfma_f32_16x16x32_f16(uz.f, w2F[0][ks],
                                                       tacc0, 0, 0, 0);
        tacc1 = __builtin_amdgcn_mfma_f32_16x16x32_f16(uz.f, w2F[1][ks],
                                                       tacc1, 0, 0, 0);
      }

      float vj[4];
#pragma unroll
      for (int j = 0; j < 4; ++j) {
        float t0 = fmaxf(tacc0[j] + bc2v0, 0.f);
        float t1 = fmaxf(tacc1[j] + bc2v1, 0.f);
        vj[j] = t0 * wc3v0 + t1 * wc3v1;
      }
#pragma unroll
      for (int m = 1; m < 16; m <<= 1) {
#pragma unroll
        for (int j = 0; j < 4; ++j) vj[j] += __shfl_xor(vj[j], m);
      }
      if (col == 0) {
#pragma unroll
        for (int j = 0; j < 4; ++j) out[eb + quad * 4 + j] = vj[j] + bc3v;
      }
    }
  }
}

extern "C" void kernel_launch(void* const* d_in, const int* in_sizes, int n_in,
                              void* d_out, int out_size, void* d_ws, size_t ws_size,
                              hipStream_t stream) {
  const int*   ei  = (const int*)d_in[1];
  const float* ea  = (const float*)d_in[2];
  const float* ns  = (const float*)d_in[3];
  const float* W1  = (const float*)d_in[4];
  const float* b1  = (const float*)d_in[5];
  const float* W2  = (const float*)d_in[6];
  const float* b2  = (const float*)d_in[7];
  const float* Wc1 = (const float*)d_in[8];
  const float* bc1 = (const float*)d_in[9];
  const float* Wc2 = (const float*)d_in[10];
  const float* bc2 = (const float*)d_in[11];
  const float* Wc3 = (const float*)d_in[12];
  const float* bc3 = (const float*)d_in[13];
  float* out = (float*)d_out;

  float*  ws     = (float*)d_ws;
  int*    deg    = (int*)ws;
  float*  agg_h0 = ws + (size_t)NN;
  float*  agg_e  = ws + (size_t)3 * NN;
  float*  agg_h1 = ws + (size_t)35 * NN;
  __half* h1h    = (__half*)(ws + (size_t)99 * NN);
  float*  W1t    = ws + (size_t)131 * NN;
  int*    bsums  = (int*)(W1t + 30000);
  int*    offs   = (int*)(ws + (size_t)132 * NN);
  int*    fill   = (int*)(ws + (size_t)133 * NN);
  int*    elist  = (int*)(ws + (size_t)134 * NN);
  int*    slist  = (int*)(ws + (size_t)150 * NN);
  __half* Pb     = (__half*)(ws + (size_t)163 * NN);  // 32NN units, ends 195NN
  __half* Qb     = (__half*)(ws + (size_t)195 * NN);  // 32NN units, ends 227NN

  hipMemsetAsync(deg, 0, NN * sizeof(int), stream);
  hipMemsetAsync(fill, 0, NN * sizeof(int), stream);

  k_wt<<<9, 256, 0, stream>>>(W1, W1t);
  k_hist<<<(NE + 255) / 256, 256, 0, stream>>>(ei, deg);
  k_scan1<<<NB_SCAN, 256, 0, stream>>>(deg, offs, bsums);
  k_scan2<<<1, 256, 0, stream>>>(bsums);
  k_scan3<<<NB_SCAN, 256, 0, stream>>>(offs, bsums);
  k_scatter<<<(NE + 255) / 256, 256, 0, stream>>>(ei, offs, fill, elist, slist);

  k_gather0<<<(NN * 32 + 255) / 256, 256, 0, stream>>>(ea, ns, offs, deg,
                                                       elist, slist, agg_h0,
                                                       agg_e);
  k_node_lin1<<<(NN * 64 + 255) / 256, 256, 0, stream>>>(ns, deg, agg_h0,
                                                         agg_e, W1t, b1, h1h);
  k_gather1<<<(NN * 64 + 255) / 256, 256, 0, stream>>>(h1h, offs, deg, slist,
                                                       agg_h1);
  k_lin2pq<<<(NN / 16 + 3) / 4, 256, 0, stream>>>(h1h, deg, agg_h1, agg_e, W2,
                                                  b2, Wc1, bc1, Pb, Qb);
  k_edge_cls<<<CLS_BLOCKS, 256, 0, stream>>>(ei, ea, Pb, Qb, Wc1, Wc2, bc2,
                                             Wc3, bc3, out);
}

// Round 9
// 292.434 us; speedup vs baseline: 5.0212x; 1.0486x over previous
//
#include <hip/hip_runtime.h>
#include <hip/hip_fp16.h>

#define NN 50000
#define NE 800000
#define NB_SCAN 196   // ceil(NN/256)
#define NB_HIST 3125  // NE/256 exactly

typedef _Float16 f16x8 __attribute__((ext_vector_type(8)));
typedef float f32x4 __attribute__((ext_vector_type(4)));
union U4 { uint4 u; f16x8 f; __half2 h2[4]; };

__device__ inline f16x8 cvt8(float4 a0, float4 a1) {
  U4 u;
  u.h2[0] = __floats2half2_rn(a0.x, a0.y);
  u.h2[1] = __floats2half2_rn(a0.z, a0.w);
  u.h2[2] = __floats2half2_rn(a1.x, a1.y);
  u.h2[3] = __floats2half2_rn(a1.z, a1.w);
  return u.f;
}

// ---- workspace layout (4B units), 227*NN floats ----
// deg i32[NN]@0 | agg_h0[2NN]@NN | agg_e[32NN]@3NN | agg_h1 f32[64NN]@35NN
// h1h f16(32NN units)@99NN..131NN | W1t@131NN(2304), bsums@131NN+30000
// offs@132NN fill@133NN | eslist int2[NE] (32NN units)@134NN..166NN
// Pb f16@163NN..195NN, Qb f16@195NN..227NN
//   (Pb clobbers eslist tail, which is dead after gathers; Qb ends at 227NN)

// ---------------- CSR hist (+ folded W1 transpose) --------------------------
__global__ __launch_bounds__(256) void k_hist(const int* __restrict__ ei,
                                              int* __restrict__ deg,
                                              const float* __restrict__ W1,
                                              float* __restrict__ W1t) {
  if (blockIdx.x >= NB_HIST) {
    int id = (blockIdx.x - NB_HIST) * 256 + threadIdx.x;
    if (id < 36 * 64) {
      int k = id >> 6, o = id & 63;
      W1t[id] = W1[o * 36 + k];
    }
    return;
  }
  int e = blockIdx.x * 256 + threadIdx.x;
  atomicAdd(&deg[ei[NE + e]], 1);
}

__global__ __launch_bounds__(256) void k_scan1(const int* __restrict__ deg,
                                               int* __restrict__ offs,
                                               int* __restrict__ bsums) {
  __shared__ int sh[256];
  int tid = threadIdx.x;
  int i = blockIdx.x * 256 + tid;
  int v = (i < NN) ? deg[i] : 0;
  int val = v;
  sh[tid] = val;
  __syncthreads();
  for (int ofs = 1; ofs < 256; ofs <<= 1) {
    int t = (tid >= ofs) ? sh[tid - ofs] : 0;
    __syncthreads();
    val += t;
    sh[tid] = val;
    __syncthreads();
  }
  if (i < NN) offs[i] = val - v;
  if (tid == 255) bsums[blockIdx.x] = val;
}

__global__ __launch_bounds__(256) void k_scan2(int* __restrict__ bsums) {
  __shared__ int sh[256];
  int tid = threadIdx.x;
  int v = (tid < NB_SCAN) ? bsums[tid] : 0;
  int val = v;
  sh[tid] = val;
  __syncthreads();
  for (int ofs = 1; ofs < 256; ofs <<= 1) {
    int t = (tid >= ofs) ? sh[tid - ofs] : 0;
    __syncthreads();
    val += t;
    sh[tid] = val;
    __syncthreads();
  }
  if (tid < NB_SCAN) bsums[tid] = val - v;
}

// offs += block base; fill seeded with the final offset (scatter uses fill only)
__global__ __launch_bounds__(256) void k_scan3(int* __restrict__ offs,
                                               const int* __restrict__ bsums,
                                               int* __restrict__ fill) {
  int i = blockIdx.x * 256 + threadIdx.x;
  if (i < NN) {
    int v = offs[i] + bsums[blockIdx.x];
    offs[i] = v;
    fill[i] = v;
  }
}

__global__ __launch_bounds__(256) void k_scatter(const int* __restrict__ ei,
                                                 int* __restrict__ fill,
                                                 int2* __restrict__ eslist) {
  int e = blockIdx.x * 256 + threadIdx.x;
  if (e >= NE) return;
  int s = ei[e];
  int d = ei[NE + e];
  int pos = atomicAdd(&fill[d], 1);
  eslist[pos] = make_int2(e, s);
}

// ---------------- gather0: 32 lanes/node, 8-edge unroll ---------------------
__global__ __launch_bounds__(256) void k_gather0(
    const float* __restrict__ ea, const float* __restrict__ ns,
    const int* __restrict__ offs, const int* __restrict__ deg,
    const int2* __restrict__ eslist, float* __restrict__ agg_h0,
    float* __restrict__ agg_e) {
  int idx = blockIdx.x * 256 + threadIdx.x;
  int n = idx >> 5, k = idx & 31;
  if (n >= NN) return;
  int off = offs[n], dg = deg[n];
  float a0 = 0.f, a1 = 0.f, a2 = 0.f, a3 = 0.f;
  float h0 = 0.f, h1v = 0.f;
  int i = 0;
  for (; i + 8 <= dg; i += 8) {
    int2 p0 = eslist[off + i + 0], p1 = eslist[off + i + 1];
    int2 p2 = eslist[off + i + 2], p3 = eslist[off + i + 3];
    int2 p4 = eslist[off + i + 4], p5 = eslist[off + i + 5];
    int2 p6 = eslist[off + i + 6], p7 = eslist[off + i + 7];
    a0 += ea[(size_t)p0.x * 32 + k];
    a1 += ea[(size_t)p1.x * 32 + k];
    a2 += ea[(size_t)p2.x * 32 + k];
    a3 += ea[(size_t)p3.x * 32 + k];
    a0 += ea[(size_t)p4.x * 32 + k];
    a1 += ea[(size_t)p5.x * 32 + k];
    a2 += ea[(size_t)p6.x * 32 + k];
    a3 += ea[(size_t)p7.x * 32 + k];
    if (k < 2) {
      h0 += ns[(size_t)p0.y * 2 + k] + ns[(size_t)p2.y * 2 + k];
      h1v += ns[(size_t)p1.y * 2 + k] + ns[(size_t)p3.y * 2 + k];
      h0 += ns[(size_t)p4.y * 2 + k] + ns[(size_t)p6.y * 2 + k];
      h1v += ns[(size_t)p5.y * 2 + k] + ns[(size_t)p7.y * 2 + k];
    }
  }
  for (; i + 2 <= dg; i += 2) {
    int2 p0 = eslist[off + i], p1 = eslist[off + i + 1];
    a0 += ea[(size_t)p0.x * 32 + k];
    a1 += ea[(size_t)p1.x * 32 + k];
    if (k < 2) {
      h0 += ns[(size_t)p0.y * 2 + k];
      h1v += ns[(size_t)p1.y * 2 + k];
    }
  }
  if (i < dg) {
    int2 p0 = eslist[off + i];
    a0 += ea[(size_t)p0.x * 32 + k];
    if (k < 2) h0 += ns[(size_t)p0.y * 2 + k];
  }
  agg_e[(size_t)n * 32 + k] = (a0 + a1) + (a2 + a3);
  if (k < 2) agg_h0[(size_t)n * 2 + k] = h0 + h1v;
}

// ---------------- gather1: wave/node, 8-row unroll --------------------------
__global__ __launch_bounds__(256) void k_gather1(
    const __half* __restrict__ h1h, const int* __restrict__ offs,
    const int* __restrict__ deg, const int2* __restrict__ eslist,
    float* __restrict__ agg_h1) {
  int idx = blockIdx.x * 256 + threadIdx.x;
  int n = idx >> 6, lane = idx & 63;
  if (n >= NN) return;
  int off = offs[n], dg = deg[n];
  float a0 = 0.f, a1 = 0.f, a2 = 0.f, a3 = 0.f;
  int i = 0;
  for (; i + 8 <= dg; i += 8) {
    int s0 = eslist[off + i + 0].y, s1 = eslist[off + i + 1].y;
    int s2 = eslist[off + i + 2].y, s3 = eslist[off + i + 3].y;
    int s4 = eslist[off + i + 4].y, s5 = eslist[off + i + 5].y;
    int s6 = eslist[off + i + 6].y, s7 = eslist[off + i + 7].y;
    a0 += __half2float(h1h[(size_t)s0 * 64 + lane]);
    a1 += __half2float(h1h[(size_t)s1 * 64 + lane]);
    a2 += __half2float(h1h[(size_t)s2 * 64 + lane]);
    a3 += __half2float(h1h[(size_t)s3 * 64 + lane]);
    a0 += __half2float(h1h[(size_t)s4 * 64 + lane]);
    a1 += __half2float(h1h[(size_t)s5 * 64 + lane]);
    a2 += __half2float(h1h[(size_t)s6 * 64 + lane]);
    a3 += __half2float(h1h[(size_t)s7 * 64 + lane]);
  }
  for (; i + 2 <= dg; i += 2) {
    int s0 = eslist[off + i].y, s1 = eslist[off + i + 1].y;
    a0 += __half2float(h1h[(size_t)s0 * 64 + lane]);
    a1 += __half2float(h1h[(size_t)s1 * 64 + lane]);
  }
  if (i < dg) a0 += __half2float(h1h[(size_t)eslist[off + i].y * 64 + lane]);
  agg_h1[(size_t)n * 64 + lane] = (a0 + a1) + (a2 + a3);
}

// ---------------- node linear 1 (vector; K=36) ------------------------------
__global__ __launch_bounds__(256) void k_node_lin1(
    const float* __restrict__ ns, const int* __restrict__ deg,
    const float* __restrict__ agg_h0, const float* __restrict__ agg_e,
    const float* __restrict__ W1t, const float* __restrict__ b1,
    __half* __restrict__ h1h) {
  int idx = blockIdx.x * 256 + threadIdx.x;
  int n = idx >> 6, o = idx & 63;
  if (n >= NN) return;
  float inv = 1.0f / fmaxf((float)deg[n], 1.0f);
  float acc = b1[o], acc2 = 0.f;
  acc += ns[n * 2 + 0] * W1t[0 * 64 + o] + ns[n * 2 + 1] * W1t[1 * 64 + o];
  acc2 += agg_h0[n * 2 + 0] * inv * W1t[2 * 64 + o] +
          agg_h0[n * 2 + 1] * inv * W1t[3 * 64 + o];
#pragma unroll
  for (int k = 0; k < 32; k += 2) {
    acc += agg_e[n * 32 + k] * inv * W1t[(4 + k) * 64 + o];
    acc2 += agg_e[n * 32 + k + 1] * inv * W1t[(5 + k) * 64 + o];
  }
  h1h[n * 64 + o] = __float2half(fmaxf(acc + acc2, 0.0f));
}

// ---------------- fused lin2 + pq: MFMA, 16-node tile per wave --------------
__global__ __launch_bounds__(256) void k_lin2pq(
    const __half* __restrict__ h1h, const int* __restrict__ deg,
    const float* __restrict__ agg_h1, const float* __restrict__ agg_e,
    const float* __restrict__ W2, const float* __restrict__ b2,
    const float* __restrict__ Wc1, const float* __restrict__ bc1,
    __half* __restrict__ Pb, __half* __restrict__ Qb) {
  __shared__ float Zt[4][16 * 68];
  int tid = threadIdx.x, lane = tid & 63, wid = tid >> 6;
  int col = lane & 15, quad = lane >> 4;
  float* zl = &Zt[wid][0];
  int task = blockIdx.x * 4 + wid;
  if (task >= NN / 16) return;  // NN = 3125*16 exactly
  int nb = task * 16;
  int nrow = nb + col;
  float inv = 1.0f / fmaxf((float)deg[nrow], 1.0f);

  f32x4 zero = {0.f, 0.f, 0.f, 0.f};
  f32x4 ce[4] = {zero, zero, zero, zero};

#pragma unroll
  for (int kc = 0; kc < 5; ++kc) {
    f16x8 af;
    if (kc < 2) {
      U4 u;
      u.u = *(const uint4*)(h1h + (size_t)nrow * 64 + kc * 32 + quad * 8);
      af = u.f;
    } else if (kc < 4) {
      const float* p = agg_h1 + (size_t)nrow * 64 + (kc - 2) * 32 + quad * 8;
      float4 a0 = ((const float4*)p)[0], a1 = ((const float4*)p)[1];
      a0.x *= inv; a0.y *= inv; a0.z *= inv; a0.w *= inv;
      a1.x *= inv; a1.y *= inv; a1.z *= inv; a1.w *= inv;
      af = cvt8(a0, a1);
    } else {
      const float* p = agg_e + (size_t)nrow * 32 + quad * 8;
      float4 a0 = ((const float4*)p)[0], a1 = ((const float4*)p)[1];
      a0.x *= inv; a0.y *= inv; a0.z *= inv; a0.w *= inv;
      a1.x *= inv; a1.y *= inv; a1.z *= inv; a1.w *= inv;
      af = cvt8(a0, a1);
    }
#pragma unroll
    for (int ob = 0; ob < 4; ++ob) {
      const float* wp = W2 + (size_t)(ob * 16 + col) * 160 + kc * 32 + quad * 8;
      f16x8 bf = cvt8(((const float4*)wp)[0], ((const float4*)wp)[1]);
      ce[ob] = __builtin_amdgcn_mfma_f32_16x16x32_f16(af, bf, ce[ob], 0, 0, 0);
    }
  }
#pragma unroll
  for (int ob = 0; ob < 4; ++ob) {
    float bv = b2[ob * 16 + col];
#pragma unroll
    for (int j = 0; j < 4; ++j)
      zl[(quad * 4 + j) * 68 + ob * 16 + col] = fmaxf(ce[ob][j] + bv, 0.f);
  }

  f32x4 pacc[4] = {zero, zero, zero, zero};
  f32x4 qacc[4] = {zero, zero, zero, zero};
#pragma unroll
  for (int kc = 0; kc < 2; ++kc) {
    const float* zc = zl + col * 68 + kc * 32 + quad * 8;
    f16x8 az = cvt8(((const float4*)zc)[0], ((const float4*)zc)[1]);
#pragma unroll
    for (int ob = 0; ob < 4; ++ob) {
      const float* wa = Wc1 + (size_t)(ob * 16 + col) * 160 + kc * 32 + quad * 8;
      f16x8 ba = cvt8(((const float4*)wa)[0], ((const float4*)wa)[1]);
      pacc[ob] = __builtin_amdgcn_mfma_f32_16x16x32_f16(az, ba, pacc[ob], 0, 0, 0);
      const float* wb = wa + 64;
      f16x8 bb = cvt8(((const float4*)wb)[0], ((const float4*)wb)[1]);
      qacc[ob] = __builtin_amdgcn_mfma_f32_16x16x32_f16(az, bb, qacc[ob], 0, 0, 0);
    }
  }
#pragma unroll
  for (int ob = 0; ob < 4; ++ob) {
    float bv = bc1[ob * 16 + col];
#pragma unroll
    for (int j = 0; j < 4; ++j) {
      int n = nb + quad * 4 + j;
      Pb[(size_t)n * 64 + ob * 16 + col] = __float2half(pacc[ob][j] + bv);
      Qb[(size_t)n * 64 + ob * 16 + col] = __float2half(qacc[ob][j]);
    }
  }
}

// ---------------- edge classifier: MFMA, hoisted ei, single LDS buf ---------
#define CLS_BLOCKS 3125  // 12500 waves, 1 task (64 edges) each
__global__ __launch_bounds__(256) void k_edge_cls(
    const int* __restrict__ ei, const float* __restrict__ ea,
    const __half* __restrict__ Pb, const __half* __restrict__ Qb,
    const float* __restrict__ Wc1, const float* __restrict__ Wc2,
    const float* __restrict__ bc2, const float* __restrict__ Wc3,
    const float* __restrict__ bc3, float* __restrict__ out) {
  __shared__ float Zt[4][16 * 68];
  int tid = threadIdx.x;
  int lane = tid & 63, wid = tid >> 6;
  int col = lane & 15, quad = lane >> 4;
  float* zl = &Zt[wid][0];

  f16x8 ctF[4];
#pragma unroll
  for (int nt = 0; nt < 4; ++nt) {
    const float* p = Wc1 + (nt * 16 + col) * 160 + 128 + quad * 8;
    ctF[nt] = cvt8(((const float4*)p)[0], ((const float4*)p)[1]);
  }
  f16x8 w2F[2][2];
#pragma unroll
  for (int nt = 0; nt < 2; ++nt)
#pragma unroll
    for (int ks = 0; ks < 2; ++ks) {
      const float* p = Wc2 + (nt * 16 + col) * 64 + ks * 32 + quad * 8;
      w2F[nt][ks] = cvt8(((const float4*)p)[0], ((const float4*)p)[1]);
    }
  float wc3v0 = Wc3[col], wc3v1 = Wc3[16 + col];
  float bc2v0 = bc2[col], bc2v1 = bc2[16 + col];
  float bc3v = bc3[0];

  int gw = blockIdx.x * 4 + wid;
  for (int task = gw; task < NE / 64; task += CLS_BLOCKS * 4) {
    int tb = task * 64;
    // hoist all 4 tiles' edge-index loads: 8 independent loads in flight
    int sArr[4], dArr[4];
#pragma unroll
    for (int mt = 0; mt < 4; ++mt) {
      sArr[mt] = ei[tb + mt * 16 + col];
      dArr[mt] = ei[NE + tb + mt * 16 + col];
    }
#pragma unroll
    for (int mt = 0; mt < 4; ++mt) {
      int eb = tb + mt * 16;
      int e = eb + col;
      int s = sArr[mt], d = dArr[mt];

      const float* eap = ea + (size_t)e * 32 + quad * 8;
      f16x8 ua = cvt8(((const float4*)eap)[0], ((const float4*)eap)[1]);
      f32x4 zero = {0.f, 0.f, 0.f, 0.f};
      f32x4 ce[4];
#pragma unroll
      for (int nt = 0; nt < 4; ++nt)
        ce[nt] = __builtin_amdgcn_mfma_f32_16x16x32_f16(ua, ctF[nt], zero,
                                                        0, 0, 0);
#pragma unroll
      for (int nt = 0; nt < 4; ++nt)
#pragma unroll
        for (int j = 0; j < 4; ++j)
          zl[(quad * 4 + j) * 68 + nt * 16 + col] = ce[nt][j];

      const __half* prow = Pb + (size_t)s * 64 + quad * 8;
      const __half* qrow = Qb + (size_t)d * 64 + quad * 8;
      f32x4 tacc0 = zero, tacc1 = zero;
#pragma unroll
      for (int ks = 0; ks < 2; ++ks) {
        U4 up, uq;
        up.u = *(const uint4*)(prow + ks * 32);
        uq.u = *(const uint4*)(qrow + ks * 32);
        const float* zc = zl + col * 68 + ks * 32 + quad * 8;
        float4 c0 = *(const float4*)(zc);
        float4 c1 = *(const float4*)(zc + 4);
        U4 uz;
        {
          float2 pf, qf;
          pf = __half22float2(up.h2[0]); qf = __half22float2(uq.h2[0]);
          uz.h2[0] = __floats2half2_rn(fmaxf(pf.x + qf.x + c0.x, 0.f),
                                       fmaxf(pf.y + qf.y + c0.y, 0.f));
          pf = __half22float2(up.h2[1]); qf = __half22float2(uq.h2[1]);
          uz.h2[1] = __floats2half2_rn(fmaxf(pf.x + qf.x + c0.z, 0.f),
                                       fmaxf(pf.y + qf.y + c0.w, 0.f));
          pf = __half22float2(up.h2[2]); qf = __half22float2(uq.h2[2]);
          uz.h2[2] = __floats2half2_rn(fmaxf(pf.x + qf.x + c1.x, 0.f),
                                       fmaxf(pf.y + qf.y + c1.y, 0.f));
          pf = __half22float2(up.h2[3]); qf = __half22float2(uq.h2[3]);
          uz.h2[3] = __floats2half2_rn(fmaxf(pf.x + qf.x + c1.z, 0.f),
                                       fmaxf(pf.y + qf.y + c1.w, 0.f));
        }
        tacc0 = __builtin_amdgcn_mfma_f32_16x16x32_f16(uz.f, w2F[0][ks],
                                                       tacc0, 0, 0, 0);
        tacc1 = __builtin_amdgcn_mfma_f32_16x16x32_f16(uz.f, w2F[1][ks],
                                                       tacc1, 0, 0, 0);
      }

      float vj[4];
#pragma unroll
      for (int j = 0; j < 4; ++j) {
        float t0 = fmaxf(tacc0[j] + bc2v0, 0.f);
        float t1 = fmaxf(tacc1[j] + bc2v1, 0.f);
        vj[j] = t0 * wc3v0 + t1 * wc3v1;
      }
#pragma unroll
      for (int m = 1; m < 16; m <<= 1) {
#pragma unroll
        for (int j = 0; j < 4; ++j) vj[j] += __shfl_xor(vj[j], m);
      }
      if (col == 0) {
#pragma unroll
        for (int j = 0; j < 4; ++j) out[eb + quad * 4 + j] = vj[j] + bc3v;
      }
    }
  }
}

extern "C" void kernel_launch(void* const* d_in, const int* in_sizes, int n_in,
                              void* d_out, int out_size, void* d_ws, size_t ws_size,
                              hipStream_t stream) {
  const int*   ei  = (const int*)d_in[1];
  const float* ea  = (const float*)d_in[2];
  const float* ns  = (const float*)d_in[3];
  const float* W1  = (const float*)d_in[4];
  const float* b1  = (const float*)d_in[5];
  const float* W2  = (const float*)d_in[6];
  const float* b2  = (const float*)d_in[7];
  const float* Wc1 = (const float*)d_in[8];
  const float* bc1 = (const float*)d_in[9];
  const float* Wc2 = (const float*)d_in[10];
  const float* bc2 = (const float*)d_in[11];
  const float* Wc3 = (const float*)d_in[12];
  const float* bc3 = (const float*)d_in[13];
  float* out = (float*)d_out;

  float*  ws     = (float*)d_ws;
  int*    deg    = (int*)ws;
  float*  agg_h0 = ws + (size_t)NN;
  float*  agg_e  = ws + (size_t)3 * NN;
  float*  agg_h1 = ws + (size_t)35 * NN;
  __half* h1h    = (__half*)(ws + (size_t)99 * NN);
  float*  W1t    = ws + (size_t)131 * NN;
  int*    bsums  = (int*)(W1t + 30000);
  int*    offs   = (int*)(ws + (size_t)132 * NN);
  int*    fill   = (int*)(ws + (size_t)133 * NN);
  int2*   eslist = (int2*)(ws + (size_t)134 * NN);   // 32NN units -> 166NN
  __half* Pb     = (__half*)(ws + (size_t)163 * NN); // clobbers eslist tail
  __half* Qb     = (__half*)(ws + (size_t)195 * NN); // ends at 227NN

  hipMemsetAsync(deg, 0, NN * sizeof(int), stream);

  k_hist<<<NB_HIST + 9, 256, 0, stream>>>(ei, deg, W1, W1t);
  k_scan1<<<NB_SCAN, 256, 0, stream>>>(deg, offs, bsums);
  k_scan2<<<1, 256, 0, stream>>>(bsums);
  k_scan3<<<NB_SCAN, 256, 0, stream>>>(offs, bsums, fill);
  k_scatter<<<NB_HIST, 256, 0, stream>>>(ei, fill, eslist);

  k_gather0<<<(NN * 32 + 255) / 256, 256, 0, stream>>>(ea, ns, offs, deg,
                                                       eslist, agg_h0, agg_e);
  k_node_lin1<<<(NN * 64 + 255) / 256, 256, 0, stream>>>(ns, deg, agg_h0,
                                                         agg_e, W1t, b1, h1h);
  k_gather1<<<(NN * 64 + 255) / 256, 256, 0, stream>>>(h1h, offs, deg, eslist,
                                                       agg_h1);
  k_lin2pq<<<(NN / 16 + 3) / 4, 256, 0, stream>>>(h1h, deg, agg_h1, agg_e, W2,
                                                  b2, Wc1, bc1, Pb, Qb);
  k_edge_cls<<<CLS_BLOCKS, 256, 0, stream>>>(ei, ea, Pb, Qb, Wc1, Wc2, bc2,
                                             Wc3, bc3, out);
}